// Round 13
// baseline (252.957 us; speedup 1.0000x reference)
//
#include <hip/hip_runtime.h>
#include <hip/hip_bf16.h>

typedef unsigned short u16;
typedef __bf16 bf16x8 __attribute__((ext_vector_type(8)));
typedef float f32x4 __attribute__((ext_vector_type(4)));

__device__ __forceinline__ u16 f2bf(float f) {
    union { float f; unsigned int u; } v; v.f = f;
    unsigned int u = v.u;
    unsigned int r = (u + 0x7fffu + ((u >> 16) & 1u)) >> 16;
    return (u16)r;
}
__device__ __forceinline__ float bf2f(u16 b) {
    union { unsigned int u; float f; } v; v.u = ((unsigned int)b) << 16;
    return v.f;
}

__device__ __forceinline__ void glds16(const u16* g, u16* l) {
    __builtin_amdgcn_global_load_lds(
        (__attribute__((address_space(1))) void*)(g),
        (__attribute__((address_space(3))) void*)(l), 16, 0, 0);
}

// ---------------- cast fp32 -> bf16 (vectorized) ----------------
__global__ __launch_bounds__(256) void cast_bf16_kernel(const float* __restrict__ src,
                                                        u16* __restrict__ dst, int n4) {
    int i = blockIdx.x * 256 + threadIdx.x;
    if (i >= n4) return;
    float4 v = ((const float4*)src)[i];
    ushort4 o;
    o.x = f2bf(v.x); o.y = f2bf(v.y); o.z = f2bf(v.z); o.w = f2bf(v.w);
    ((ushort4*)dst)[i] = o;
}

// ---------------- transpose+cast weights: WT[n][k] = W[k][n] ----------------
__global__ __launch_bounds__(256) void transpose_cast_kernel(
    const float* __restrict__ Wq, const float* __restrict__ Wk, const float* __restrict__ Wv,
    const float* __restrict__ Wg, const float* __restrict__ Wo,
    u16* __restrict__ WqT, u16* __restrict__ WkvT, u16* __restrict__ WgT, u16* __restrict__ WoT) {
    __shared__ float tile[32][33];
    const float* src; u16* dst;
    switch (blockIdx.z) {
        case 0: src = Wq; dst = WqT; break;
        case 1: src = Wk; dst = WkvT; break;
        case 2: src = Wv; dst = WkvT + (size_t)1024 * 1024; break;
        case 3: src = Wg; dst = WgT; break;
        default: src = Wo; dst = WoT; break;
    }
    int n0 = blockIdx.x * 32, k0 = blockIdx.y * 32;
    int tx = threadIdx.x, ty = threadIdx.y;   // (32, 8)
    #pragma unroll
    for (int j = 0; j < 4; j++)
        tile[ty + j * 8][tx] = src[(size_t)(k0 + ty + j * 8) * 1024 + n0 + tx];
    __syncthreads();
    #pragma unroll
    for (int j = 0; j < 4; j++)
        dst[(size_t)(n0 + ty + j * 8) * 1024 + k0 + tx] = f2bf(tile[tx][ty + j * 8]);
}

// ---------------- 128^2 bf16 MFMA GEMM (m97 structure) ----------------
template <int EPI>
__global__ __launch_bounds__(256) void gemm_bf16(
    const u16* __restrict__ A, const u16* __restrict__ B, int ldc,
    u16* __restrict__ Cbf, const float* __restrict__ bias,
    const u16* __restrict__ mul_src, const float* __restrict__ add_src,
    float* __restrict__ Cf) {
    constexpr int K = 1024;
    const int tid = threadIdx.x;
    const int w = tid >> 6, l = tid & 63;
    const int lr = l & 15, lg = l >> 4;
    const int wr = w >> 1, wc = w & 1;
    const int m0 = blockIdx.y * 128, n0 = blockIdx.x * 128;

    __shared__ u16 As[128 * 64];
    __shared__ u16 Bs[128 * 64];

    const f32x4 fz = {0.f, 0.f, 0.f, 0.f};
    f32x4 acc[4][4];
    #pragma unroll
    for (int i = 0; i < 4; i++)
        #pragma unroll
        for (int j = 0; j < 4; j++) acc[i][j] = fz;

    const int lane_row = l >> 3;
    const int lane_sl  = l & 7;
    const int src_ch   = lane_sl ^ lane_row;
    const u16* Ab = A + (size_t)(m0 + w * 32 + lane_row) * K + src_ch * 8;
    const u16* Bb = B + (size_t)(n0 + w * 32 + lane_row) * K + src_ch * 8;

    for (int kt = 0; kt < K; kt += 64) {
        __syncthreads();
        #pragma unroll
        for (int j = 0; j < 4; j++) {
            glds16(Ab + (size_t)j * 8 * K + kt, As + (w * 32 + j * 8) * 64);
            glds16(Bb + (size_t)j * 8 * K + kt, Bs + (w * 32 + j * 8) * 64);
        }
        __syncthreads();
        #pragma unroll
        for (int kk = 0; kk < 2; kk++) {
            bf16x8 af[4], bfr[4];
            #pragma unroll
            for (int mi = 0; mi < 4; mi++) {
                int row = wr * 64 + mi * 16 + lr;
                int ch = (kk * 4 + lg) ^ (row & 7);
                af[mi] = *(const bf16x8*)(As + row * 64 + ch * 8);
            }
            #pragma unroll
            for (int ni = 0; ni < 4; ni++) {
                int row = wc * 64 + ni * 16 + lr;
                int ch = (kk * 4 + lg) ^ (row & 7);
                bfr[ni] = *(const bf16x8*)(Bs + row * 64 + ch * 8);
            }
            #pragma unroll
            for (int mi = 0; mi < 4; mi++)
                #pragma unroll
                for (int ni = 0; ni < 4; ni++)
                    acc[mi][ni] = __builtin_amdgcn_mfma_f32_16x16x32_bf16(
                        af[mi], bfr[ni], acc[mi][ni], 0, 0, 0);
        }
    }

    #pragma unroll
    for (int mi = 0; mi < 4; mi++) {
        #pragma unroll
        for (int ni = 0; ni < 4; ni++) {
            #pragma unroll
            for (int r = 0; r < 4; r++) {
                int gm = m0 + wr * 64 + mi * 16 + lg * 4 + r;
                int gn = n0 + wc * 64 + ni * 16 + lr;
                float v = acc[mi][ni][r];
                if (EPI == 0) {
                    Cbf[(size_t)gm * ldc + gn] = f2bf(v);
                } else if (EPI == 2) {
                    float g = v + bias[gn];
                    float a = bf2f(mul_src[(size_t)gm * ldc + gn]);
                    float sg = 1.f / (1.f + __expf(-g));
                    Cbf[(size_t)gm * ldc + gn] = f2bf(a * sg);
                } else {
                    Cf[(size_t)gm * ldc + gn] = v + bias[gn] + add_src[(size_t)gm * ldc + gn];
                }
            }
        }
    }
}

// ---------------- hidden column-sum, stage 1 ----------------
__global__ __launch_bounds__(256) void hsum1_kernel(const float* __restrict__ hidden,
                                                    float* __restrict__ part) {
    int b = blockIdx.x, chunk = blockIdx.y;   // (2, 128)
    int tid = threadIdx.x;
    const float4* src = (const float4*)(hidden + ((size_t)b * 2048 + chunk * 16) * 1024) + tid;
    float4 acc = {0.f, 0.f, 0.f, 0.f};
    #pragma unroll
    for (int r = 0; r < 16; r++) {
        float4 v = src[r * 256];
        acc.x += v.x; acc.y += v.y; acc.z += v.z; acc.w += v.w;
    }
    ((float4*)(part + ((size_t)b * 128 + chunk) * 1024))[tid] = acc;
}

// ---------------- stage 2: mean ----------------
__global__ __launch_bounds__(256) void hsum2_kernel(const float* __restrict__ part,
                                                    float* __restrict__ hm) {
    int b = blockIdx.x, tid = threadIdx.x;
    const float4* src = (const float4*)(part + (size_t)b * 128 * 1024) + tid;
    float4 acc = {0.f, 0.f, 0.f, 0.f};
    for (int c = 0; c < 128; c++) {
        float4 v = src[c * 256];
        acc.x += v.x; acc.y += v.y; acc.z += v.z; acc.w += v.w;
    }
    const float inv = 1.f / 2048.f;
    acc.x *= inv; acc.y *= inv; acc.z *= inv; acc.w *= inv;
    ((float4*)(hm + (size_t)b * 1024))[tid] = acc;
}

// ---------------- qz ----------------
__global__ __launch_bounds__(256) void qz_kernel(const float* __restrict__ hm,
                                                 const u16* __restrict__ WqT,
                                                 const u16* __restrict__ WkT,
                                                 u16* __restrict__ z_bf) {
    int bh = blockIdx.x, b = bh >> 4, h = bh & 15;
    int tid = threadIdx.x;
    __shared__ float hm_l[1024];
    __shared__ float qs_l[64];
    __shared__ float red[256];
    ((float4*)hm_l)[tid] = ((const float4*)(hm + (size_t)b * 1024))[tid];
    __syncthreads();
    {
        int d = tid >> 2, q = tid & 3;
        const u16* wq = WqT + (size_t)(h * 64 + d) * 1024 + q * 256;
        float a = 0.f;
        for (int i = 0; i < 256; i += 8) {
            uint4 u = *(const uint4*)(wq + i);
            const u16* p = (const u16*)&u;
            #pragma unroll
            for (int j = 0; j < 8; j++) a += bf2f(p[j]) * hm_l[q * 256 + i + j];
        }
        red[tid] = a;
    }
    __syncthreads();
    if (tid < 64)
        qs_l[tid] = red[tid * 4] + red[tid * 4 + 1] + red[tid * 4 + 2] + red[tid * 4 + 3];
    __syncthreads();
    {
        float z0 = 0.f, z1 = 0.f, z2 = 0.f, z3 = 0.f;
        for (int d = 0; d < 64; d++) {
            float qs = qs_l[d];
            const u16* wk = WkT + (size_t)(h * 64 + d) * 1024 + tid * 4;
            uint2 u = *(const uint2*)wk;
            const u16* p = (const u16*)&u;
            z0 += qs * bf2f(p[0]); z1 += qs * bf2f(p[1]);
            z2 += qs * bf2f(p[2]); z3 += qs * bf2f(p[3]);
        }
        ushort4 o;
        o.x = f2bf(z0); o.y = f2bf(z1); o.z = f2bf(z2); o.w = f2bf(z3);
        *(ushort4*)(z_bf + (size_t)bh * 1024 + tid * 4) = o;
    }
}

// ---------------- score v3: barrier-free MFMA score over bf16 enc ----------------
// 64 kv rows/block, grid (256,2). Each wave stages & reads ONLY its own 16 rows
// -> no cross-wave LDS sharing -> no barriers, just counted vmcnt.
__global__ __launch_bounds__(256) void score_kernel(const u16* __restrict__ ebf,
                                                    const u16* __restrict__ z_bf,
                                                    float* __restrict__ score) {
    const int b = blockIdx.y, kv0 = blockIdx.x * 64;
    const int tid = threadIdx.x, w = tid >> 6, l = tid & 63;
    const int lr = l & 15, lg = l >> 4;
    __shared__ u16 e_lds[2][64 * 64];   // 16 KB dbuf

    const u16* eb = ebf + (size_t)(b * 16384 + kv0) * 1024;
    const u16* zb = z_bf + (size_t)b * 16 * 1024;
    const int lrow = l >> 3, lch = l & 7;
    const int src_ch = lch ^ lrow;

    auto stage = [&](int kt, int buf) {
        const u16* s0 = eb + (size_t)(w * 16 + lrow) * 1024 + kt + src_ch * 8;
        glds16(s0,            e_lds[buf] + (w * 16) * 64);
        glds16(s0 + 8 * 1024, e_lds[buf] + (w * 16 + 8) * 64);
    };
    stage(0, 0);

    const f32x4 fz = {0.f, 0.f, 0.f, 0.f};
    f32x4 acc = fz;

    #pragma unroll 1
    for (int t = 0; t < 16; ++t) {
        const int kt = t * 64;
        if (t + 1 < 16) {
            stage(kt + 64, (t & 1) ^ 1);
            asm volatile("s_waitcnt vmcnt(2)" ::: "memory");   // cur buf's 2 loads done
        } else {
            asm volatile("s_waitcnt vmcnt(0)" ::: "memory");
        }
        __builtin_amdgcn_sched_barrier(0);
        const u16* ecur = e_lds[t & 1];
        #pragma unroll
        for (int ks = 0; ks < 2; ks++) {
            bf16x8 af = *(const bf16x8*)(zb + (size_t)lr * 1024 + kt + ks * 32 + lg * 8);
            int row = w * 16 + lr;
            bf16x8 bf_ = *(const bf16x8*)(ecur + row * 64 + (((ks * 4 + lg) ^ (row & 7))) * 8);
            acc = __builtin_amdgcn_mfma_f32_16x16x32_bf16(af, bf_, acc, 0, 0, 0);
        }
    }
    #pragma unroll
    for (int r = 0; r < 4; r++)
        score[(size_t)(b * 16 + lg * 4 + r) * 16384 + kv0 + w * 16 + lr] = acc[r];
}

// ---------------- top-2048 select: 16-bit keys, single sweep, 1024 threads ----------------
__global__ __launch_bounds__(1024) void select_kernel(const float* __restrict__ score,
                                                      int* __restrict__ sel_idx) {
    const int bh = blockIdx.x;
    const float* sc = score + (size_t)bh * 16384;
    const int tid = threadIdx.x;
    const int grp = tid >> 8;

    __shared__ int hist[4][256];
    __shared__ int total[256];
    __shared__ int bc[4];

    u16 key[16];
    #pragma unroll
    for (int j = 0; j < 16; j++) {
        unsigned int b = __float_as_uint(sc[tid + j * 1024]);
        unsigned int ui = (b & 0x80000000u) ? ~b : (b | 0x80000000u);
        key[j] = (u16)(ui >> 16);
    }

    ((int*)hist)[tid] = 0;
    __syncthreads();
    #pragma unroll
    for (int j = 0; j < 16; j++) atomicAdd(&hist[grp][key[j] >> 8], 1);
    __syncthreads();
    if (tid < 256) total[tid] = hist[0][tid] + hist[1][tid] + hist[2][tid] + hist[3][tid];
    __syncthreads();
    if (tid == 0) {
        int want = 2048, acc = 0;
        for (int dd = 255; dd >= 0; dd--) {
            acc += total[dd];
            if (acc >= want) { bc[0] = dd; bc[1] = want - (acc - total[dd]); break; }
        }
    }
    __syncthreads();
    const int hi = bc[0];
    const int want1 = bc[1];

    ((int*)hist)[tid] = 0;
    __syncthreads();
    #pragma unroll
    for (int j = 0; j < 16; j++)
        if ((key[j] >> 8) == hi) atomicAdd(&hist[grp][key[j] & 0xff], 1);
    __syncthreads();
    if (tid < 256) total[tid] = hist[0][tid] + hist[1][tid] + hist[2][tid] + hist[3][tid];
    __syncthreads();
    if (tid == 0) {
        int want = want1, acc = 0;
        for (int dd = 255; dd >= 0; dd--) {
            acc += total[dd];
            if (acc >= want) { bc[0] = (hi << 8) | dd; bc[1] = want - (acc - total[dd]); break; }
        }
        bc[2] = 0; bc[3] = 0;
    }
    __syncthreads();
    const u16 thr = (u16)bc[0];
    const int n_eq = bc[1];
    const int base_eq = 2048 - n_eq;

    int* out = sel_idx + (size_t)bh * 2048;
    #pragma unroll
    for (int j = 0; j < 16; j++) {
        int i = tid + j * 1024;
        if (key[j] > thr) {
            int p = atomicAdd(&bc[2], 1);
            out[p] = i;
        } else if (key[j] == thr) {
            int p = atomicAdd(&bc[3], 1);
            if (p < n_eq) out[base_eq + p] = i;
        }
    }
}

// ---------------- selected projection (dbuf pipelined): K_sel + V_selT(kappa) ----------------
__global__ __launch_bounds__(256) void selproj_kernel(const u16* __restrict__ ebf,
                                                      const u16* __restrict__ WkvT,
                                                      const int* __restrict__ sel_idx,
                                                      u16* __restrict__ k_sel,
                                                      u16* __restrict__ v_selT) {
    const int bh = blockIdx.y, b = bh >> 4, h = bh & 15;
    const int t0 = blockIdx.x * 128;
    const int tid = threadIdx.x, w = tid >> 6, l = tid & 63;
    const int lr = l & 15, lg = l >> 4;
    const int lane_row = l >> 3, src_ch = (l & 7) ^ lane_row;

    __shared__ u16 e_lds[2][128 * 64];   // 32 KB
    __shared__ u16 w_lds[2][128 * 64];   // 32 KB

    int encrow[4], wrow[4];
    #pragma unroll
    for (int j = 0; j < 4; j++) {
        int t = t0 + w * 32 + j * 8 + lane_row;
        encrow[j] = b * 16384 + sel_idx[(size_t)bh * 2048 + t];
        int r = w * 32 + j * 8 + lane_row;
        wrow[j] = (r < 64) ? (h * 64 + r) : (1024 + h * 64 + (r & 63));
    }

    auto stage = [&](int kt, int buf) {
        #pragma unroll
        for (int j = 0; j < 4; j++) {
            glds16(ebf + (size_t)encrow[j] * 1024 + kt + src_ch * 8,
                   e_lds[buf] + (w * 32 + j * 8) * 64);
            glds16(WkvT + (size_t)wrow[j] * 1024 + kt + src_ch * 8,
                   w_lds[buf] + (w * 32 + j * 8) * 64);
        }
    };

    const f32x4 fz = {0.f, 0.f, 0.f, 0.f};
    f32x4 acc_k[2][4], acc_v[8];
    #pragma unroll
    for (int i = 0; i < 2; i++)
        #pragma unroll
        for (int j = 0; j < 4; j++) acc_k[i][j] = fz;
    #pragma unroll
    for (int i = 0; i < 8; i++) acc_v[i] = fz;

    stage(0, 0);
    __syncthreads();   // drain tile0

    #pragma unroll 1
    for (int t = 0; t < 16; ++t) {
        const int kt = t * 64;
        const int cur = t & 1;
        if (t + 1 < 16) stage(kt + 64, cur ^ 1);   // issue next tile EARLY

        const u16* ec = e_lds[cur];
        const u16* wc_ = w_lds[cur];
        __builtin_amdgcn_s_setprio(1);
        #pragma unroll
        for (int ks = 0; ks < 2; ks++) {
            bf16x8 ae[2];
            #pragma unroll
            for (int mi = 0; mi < 2; mi++) {
                int row = w * 32 + mi * 16 + lr;
                ae[mi] = *(const bf16x8*)(ec + row * 64 + (((ks * 4 + lg) ^ (row & 7))) * 8);
            }
            bf16x8 aw;
            {
                int row = 64 + w * 16 + lr;
                aw = *(const bf16x8*)(wc_ + row * 64 + (((ks * 4 + lg) ^ (row & 7))) * 8);
            }
            #pragma unroll
            for (int ni = 0; ni < 4; ni++) {
                int row = ni * 16 + lr;
                bf16x8 bw = *(const bf16x8*)(wc_ + row * 64 + (((ks * 4 + lg) ^ (row & 7))) * 8);
                acc_k[0][ni] = __builtin_amdgcn_mfma_f32_16x16x32_bf16(ae[0], bw, acc_k[0][ni], 0, 0, 0);
                acc_k[1][ni] = __builtin_amdgcn_mfma_f32_16x16x32_bf16(ae[1], bw, acc_k[1][ni], 0, 0, 0);
            }
            #pragma unroll
            for (int ni = 0; ni < 8; ni++) {
                int row = ni * 16 + lr;
                bf16x8 be = *(const bf16x8*)(ec + row * 64 + (((ks * 4 + lg) ^ (row & 7))) * 8);
                acc_v[ni] = __builtin_amdgcn_mfma_f32_16x16x32_bf16(aw, be, acc_v[ni], 0, 0, 0);
            }
        }
        __builtin_amdgcn_s_setprio(0);
        __syncthreads();   // drains next-tile loads (hidden under 32 MFMAs) + read fence
    }

    u16* kb = k_sel + (size_t)bh * 2048 * 64;
    #pragma unroll
    for (int mi = 0; mi < 2; mi++)
        #pragma unroll
        for (int ni = 0; ni < 4; ni++)
            #pragma unroll
            for (int r = 0; r < 4; r++) {
                int t = t0 + w * 32 + mi * 16 + lg * 4 + r;
                int d = ni * 16 + lr;
                kb[(size_t)t * 64 + (((d >> 3) ^ (t & 7)) * 8) + (d & 7)] = f2bf(acc_k[mi][ni][r]);
            }
    u16* vb = v_selT + (size_t)bh * 64 * 2048;
    #pragma unroll
    for (int ni = 0; ni < 8; ni++)
        #pragma unroll
        for (int r = 0; r < 4; r++) {
            int d = w * 16 + lg * 4 + r;
            int t = t0 + ni * 16 + lr;
            int tl = t & 63;
            int kap = (tl & 15) * 4 + (tl >> 4);
            vb[(size_t)d * 2048 + (t & ~63) + (((kap >> 3) ^ (d & 7)) * 8) + (kap & 7)] =
                f2bf(acc_v[ni][r]);
        }
}

// ---------------- flash attention: 8 waves, QBLK=128, kappa-packed P store ----------------
__global__ __launch_bounds__(512) void attn_kernel(
    const u16* __restrict__ q_bf, const u16* __restrict__ k_sel,
    const u16* __restrict__ v_selT, u16* __restrict__ attn_out) {
    const int bh = blockIdx.y, b = bh >> 4, h = bh & 15;
    const int q0 = blockIdx.x * 128;
    const int tid = threadIdx.x, w = tid >> 6, l = tid & 63;
    const int lr = l & 15, lg = l >> 4;
    const int lk = lr & 7;
    const float SC = 0.18033688011f;   // 0.125 * log2(e)
    const float THR = 11.0f;

    __shared__ u16 k_lds[2][64 * 64];
    __shared__ u16 vt_lds[64 * 64];
    __shared__ u16 p_lds[8][16][68];

    const u16* qb = q_bf + ((size_t)b * 2048 + q0 + w * 16 + lr) * 1024 + h * 64;
    bf16x8 qf0 = *(const bf16x8*)(qb + lg * 8);
    bf16x8 qf1 = *(const bf16x8*)(qb + 32 + lg * 8);

    const f32x4 fz = {0.f, 0.f, 0.f, 0.f};
    f32x4 o[4];
    #pragma unroll
    for (int f = 0; f < 4; f++) o[f] = fz;
    float mm = -1e30f;
    float l_part[4] = {0.f, 0.f, 0.f, 0.f};

    const u16* kb  = k_sel + (size_t)bh * 2048 * 64;
    const u16* vtb = v_selT + (size_t)bh * 64 * 2048;

    auto stageK = [&](int it, int buf) {
        const u16* ksrc = kb + (size_t)(it * 64 + w * 8) * 64 + (size_t)l * 8;
        glds16(ksrc, k_lds[buf] + (w * 8) * 64);
    };
    auto stageV = [&](int it) {
        const u16* vsrc = vtb + (size_t)(w * 8 + (l >> 3)) * 2048 + it * 64 + (l & 7) * 8;
        glds16(vsrc, vt_lds + (w * 8) * 64);
    };

    stageK(0, 0);
    __syncthreads();

    #pragma unroll 1
    for (int it = 0; it < 32; ++it) {
        const int cur = it & 1;
        stageV(it);
        if (it + 1 < 32) stageK(it + 1, cur ^ 1);

        f32x4 s[4];
        #pragma unroll
        for (int c = 0; c < 4; c++) s[c] = fz;
        __builtin_amdgcn_s_setprio(1);
        #pragma unroll
        for (int c = 0; c < 4; c++) {
            const u16* krow = k_lds[cur] + (c * 16 + lr) * 64;
            bf16x8 kf0 = *(const bf16x8*)(krow + (lg ^ lk) * 8);
            s[c] = __builtin_amdgcn_mfma_f32_16x16x32_bf16(qf0, kf0, s[c], 0, 0, 0);
            bf16x8 kf1 = *(const bf16x8*)(krow + (((4 + lg) ^ lk)) * 8);
            s[c] = __builtin_amdgcn_mfma_f32_16x16x32_bf16(qf1, kf1, s[c], 0, 0, 0);
        }
        __builtin_amdgcn_s_setprio(0);

        float mx = s[0][0];
        #pragma unroll
        for (int c = 0; c < 4; c++)
            #pragma unroll
            for (int r = 0; r < 4; r++) mx = fmaxf(mx, s[c][r]);
        mx = fmaxf(mx, __shfl_xor(mx, 1));
        mx = fmaxf(mx, __shfl_xor(mx, 2));
        mx = fmaxf(mx, __shfl_xor(mx, 4));
        mx = fmaxf(mx, __shfl_xor(mx, 8));
        mx = fmaxf(mx, __shfl_xor(mx, 16));
        mx = fmaxf(mx, __shfl_xor(mx, 32));
        mx *= SC;
        if (mx > mm + THR) {
            float al = __builtin_amdgcn_exp2f(mm - mx);
            mm = mx;
            #pragma unroll
            for (int r = 0; r < 4; r++) l_part[r] *= al;
            #pragma unroll
            for (int f = 0; f < 4; f++)
                #pragma unroll
                for (int r = 0; r < 4; r++) o[f][r] *= al;
        }
        #pragma unroll
        for (int r = 0; r < 4; r++) {
            ushort4 pk;
            u16 pb[4];
            #pragma unroll
            for (int c = 0; c < 4; c++) {
                float p = __builtin_amdgcn_exp2f(__builtin_fmaf(s[c][r], SC, -mm));
                l_part[r] += p;
                __bf16 hv = (__bf16)p;
                pb[c] = *(u16*)&hv;
            }
            pk.x = pb[0]; pk.y = pb[1]; pk.z = pb[2]; pk.w = pb[3];
            *(ushort4*)(&p_lds[w][lg * 4 + r][lr * 4]) = pk;
        }

        if (it + 1 < 32) {
            asm volatile("s_waitcnt vmcnt(1)" ::: "memory");
        } else {
            asm volatile("s_waitcnt vmcnt(0)" ::: "memory");
        }
        __builtin_amdgcn_sched_barrier(0);
        __builtin_amdgcn_s_barrier();

        __builtin_amdgcn_s_setprio(1);
        #pragma unroll
        for (int kk = 0; kk < 2; kk++) {
            bf16x8 ap = *(const bf16x8*)(&p_lds[w][lr][kk * 32 + lg * 8]);
            #pragma unroll
            for (int f = 0; f < 4; f++) {
                const u16* vrow = vt_lds + (f * 16 + lr) * 64;
                bf16x8 bv = *(const bf16x8*)(vrow + (((kk * 4 + lg) ^ lk)) * 8);
                o[f] = __builtin_amdgcn_mfma_f32_16x16x32_bf16(ap, bv, o[f], 0, 0, 0);
            }
        }
        __builtin_amdgcn_s_setprio(0);

        __syncthreads();
    }

    float invl[4];
    #pragma unroll
    for (int r = 0; r < 4; r++) {
        float lr_ = l_part[r];
        lr_ += __shfl_xor(lr_, 1);
        lr_ += __shfl_xor(lr_, 2);
        lr_ += __shfl_xor(lr_, 4);
        lr_ += __shfl_xor(lr_, 8);
        invl[r] = 1.f / lr_;
    }
    u16* ob = attn_out + ((size_t)b * 2048 + q0 + w * 16 + lg * 4) * 1024 + h * 64 + lr;
    #pragma unroll
    for (int f = 0; f < 4; f++) {
        #pragma unroll
        for (int r = 0; r < 4; r++) {
            __bf16 hv = (__bf16)(o[f][r] * invl[r]);
            ob[(size_t)r * 1024 + f * 16] = *(u16*)&hv;
        }
    }
}

// ---------------- launcher ----------------
extern "C" void kernel_launch(void* const* d_in, const int* in_sizes, int n_in,
                              void* d_out, int out_size, void* d_ws, size_t ws_size,
                              hipStream_t stream) {
    const float* hidden = (const float*)d_in[0];
    const float* enc    = (const float*)d_in[1];
    const float* Wq = (const float*)d_in[2];
    const float* Wk = (const float*)d_in[3];
    const float* Wv = (const float*)d_in[4];
    const float* Wo = (const float*)d_in[5];
    const float* bo = (const float*)d_in[6];
    const float* Wg = (const float*)d_in[7];
    const float* bg = (const float*)d_in[8];
    float* out = (float*)d_out;

    char* ws = (char*)d_ws;
    size_t off = 0;
    auto alloc = [&](size_t bytes) -> char* {
        char* p = ws + off;
        off += (bytes + 255) & ~(size_t)255;
        return p;
    };
    u16* hbf   = (u16*)alloc(4096ull * 1024 * 2);
    u16* ebf   = (u16*)alloc(32768ull * 1024 * 2);
    u16* WqT   = (u16*)alloc(1024ull * 1024 * 2);
    u16* WkvT  = (u16*)alloc(2048ull * 1024 * 2);
    u16* WgT   = (u16*)alloc(1024ull * 1024 * 2);
    u16* WoT   = (u16*)alloc(1024ull * 1024 * 2);
    u16* q_bf  = (u16*)alloc(4096ull * 1024 * 2);
    float* hm  = (float*)alloc(2ull * 1024 * 4);
    float* part = (float*)alloc(2ull * 128 * 1024 * 4);
    u16* z_bf  = (u16*)alloc(32ull * 1024 * 2);
    float* scor = (float*)alloc(32ull * 16384 * 4);
    int* sel    = (int*)alloc(32ull * 2048 * 4);
    u16* ksel   = (u16*)alloc(32ull * 2048 * 64 * 2);
    u16* vT     = (u16*)alloc(32ull * 64 * 2048 * 2);
    u16* attn   = (u16*)alloc(4096ull * 1024 * 2);
    u16* gate   = (u16*)alloc(4096ull * 1024 * 2);
    (void)ws_size; (void)in_sizes; (void)n_in; (void)out_size;

    hsum1_kernel<<<dim3(2, 128), 256, 0, stream>>>(hidden, part);
    hsum2_kernel<<<2, 256, 0, stream>>>(part, hm);
    cast_bf16_kernel<<<4096, 256, 0, stream>>>(hidden, hbf, 1048576);
    cast_bf16_kernel<<<32768, 256, 0, stream>>>(enc, ebf, 8388608);
    transpose_cast_kernel<<<dim3(32, 32, 5), dim3(32, 8), 0, stream>>>(
        Wq, Wk, Wv, Wg, Wo, WqT, WkvT, WgT, WoT);

    qz_kernel<<<32, 256, 0, stream>>>(hm, WqT, WkvT, z_bf);
    score_kernel<<<dim3(256, 2), 256, 0, stream>>>(ebf, z_bf, scor);
    select_kernel<<<32, 1024, 0, stream>>>(scor, sel);
    selproj_kernel<<<dim3(16, 32), 256, 0, stream>>>(ebf, WkvT, sel, ksel, vT);

    gemm_bf16<0><<<dim3(8, 32), 256, 0, stream>>>(hbf, WqT, 1024, q_bf, nullptr, nullptr, nullptr, nullptr);
    attn_kernel<<<dim3(16, 32), 512, 0, stream>>>(q_bf, ksel, vT, attn);

    gemm_bf16<2><<<dim3(8, 32), 256, 0, stream>>>(attn, WgT, 1024, gate, bg, attn, nullptr, nullptr);
    gemm_bf16<3><<<dim3(8, 32), 256, 0, stream>>>(gate, WoT, 1024, nullptr, bo, nullptr, hidden, out);
}

// Round 14
// 249.534 us; speedup vs baseline: 1.0137x; 1.0137x over previous
//
#include <hip/hip_runtime.h>
#include <hip/hip_bf16.h>

typedef unsigned short u16;
typedef __bf16 bf16x8 __attribute__((ext_vector_type(8)));
typedef float f32x4 __attribute__((ext_vector_type(4)));

__device__ __forceinline__ u16 f2bf(float f) {
    union { float f; unsigned int u; } v; v.f = f;
    unsigned int u = v.u;
    unsigned int r = (u + 0x7fffu + ((u >> 16) & 1u)) >> 16;
    return (u16)r;
}
__device__ __forceinline__ float bf2f(u16 b) {
    union { unsigned int u; float f; } v; v.u = ((unsigned int)b) << 16;
    return v.f;
}

__device__ __forceinline__ void glds16(const u16* g, u16* l) {
    __builtin_amdgcn_global_load_lds(
        (__attribute__((address_space(1))) void*)(g),
        (__attribute__((address_space(3))) void*)(l), 16, 0, 0);
}

// ---------------- cast fp32 -> bf16 (enc) ----------------
__global__ __launch_bounds__(256) void cast_bf16_kernel(const float* __restrict__ src,
                                                        u16* __restrict__ dst, int n4) {
    int i = blockIdx.x * 256 + threadIdx.x;
    if (i >= n4) return;
    float4 v = ((const float4*)src)[i];
    ushort4 o;
    o.x = f2bf(v.x); o.y = f2bf(v.y); o.z = f2bf(v.z); o.w = f2bf(v.w);
    ((ushort4*)dst)[i] = o;
}

// ---------------- prep: fused hidden cast + column partial sums ----------------
__global__ __launch_bounds__(256) void prep_kernel(const float* __restrict__ hidden,
                                                   u16* __restrict__ hbf,
                                                   float* __restrict__ part) {
    int b = blockIdx.x, chunk = blockIdx.y;   // (2, 128)
    int tid = threadIdx.x;
    const float4* src = (const float4*)(hidden + ((size_t)b * 2048 + chunk * 16) * 1024) + tid;
    u16* dst = hbf + ((size_t)b * 2048 + chunk * 16) * 1024 + tid * 4;
    float4 acc = {0.f, 0.f, 0.f, 0.f};
    #pragma unroll
    for (int r = 0; r < 16; r++) {
        float4 v = src[r * 256];
        acc.x += v.x; acc.y += v.y; acc.z += v.z; acc.w += v.w;
        ushort4 o;
        o.x = f2bf(v.x); o.y = f2bf(v.y); o.z = f2bf(v.z); o.w = f2bf(v.w);
        *(ushort4*)(dst + (size_t)r * 1024) = o;
    }
    ((float4*)(part + ((size_t)b * 128 + chunk) * 1024))[tid] = acc;
}

// ---------------- transpose+cast weights: WT[n][k] = W[k][n] ----------------
__global__ __launch_bounds__(256) void transpose_cast_kernel(
    const float* __restrict__ Wq, const float* __restrict__ Wk, const float* __restrict__ Wv,
    const float* __restrict__ Wg, const float* __restrict__ Wo,
    u16* __restrict__ WqT, u16* __restrict__ WkvT, u16* __restrict__ WgT, u16* __restrict__ WoT) {
    __shared__ float tile[32][33];
    const float* src; u16* dst;
    switch (blockIdx.z) {
        case 0: src = Wq; dst = WqT; break;
        case 1: src = Wk; dst = WkvT; break;
        case 2: src = Wv; dst = WkvT + (size_t)1024 * 1024; break;
        case 3: src = Wg; dst = WgT; break;
        default: src = Wo; dst = WoT; break;
    }
    int n0 = blockIdx.x * 32, k0 = blockIdx.y * 32;
    int tx = threadIdx.x, ty = threadIdx.y;   // (32, 8)
    #pragma unroll
    for (int j = 0; j < 4; j++)
        tile[ty + j * 8][tx] = src[(size_t)(k0 + ty + j * 8) * 1024 + n0 + tx];
    __syncthreads();
    #pragma unroll
    for (int j = 0; j < 4; j++)
        dst[(size_t)(n0 + ty + j * 8) * 1024 + k0 + tx] = f2bf(tile[tx][ty + j * 8]);
}

// ---------------- 128^2 bf16 MFMA GEMM (m97 structure) ----------------
template <int EPI>
__global__ __launch_bounds__(256) void gemm_bf16(
    const u16* __restrict__ A, const u16* __restrict__ B, int ldc,
    u16* __restrict__ Cbf, const float* __restrict__ bias,
    const u16* __restrict__ mul_src, const float* __restrict__ add_src,
    float* __restrict__ Cf) {
    constexpr int K = 1024;
    const int tid = threadIdx.x;
    const int w = tid >> 6, l = tid & 63;
    const int lr = l & 15, lg = l >> 4;
    const int wr = w >> 1, wc = w & 1;
    const int m0 = blockIdx.y * 128, n0 = blockIdx.x * 128;

    __shared__ u16 As[128 * 64];
    __shared__ u16 Bs[128 * 64];

    const f32x4 fz = {0.f, 0.f, 0.f, 0.f};
    f32x4 acc[4][4];
    #pragma unroll
    for (int i = 0; i < 4; i++)
        #pragma unroll
        for (int j = 0; j < 4; j++) acc[i][j] = fz;

    const int lane_row = l >> 3;
    const int lane_sl  = l & 7;
    const int src_ch   = lane_sl ^ lane_row;
    const u16* Ab = A + (size_t)(m0 + w * 32 + lane_row) * K + src_ch * 8;
    const u16* Bb = B + (size_t)(n0 + w * 32 + lane_row) * K + src_ch * 8;

    for (int kt = 0; kt < K; kt += 64) {
        __syncthreads();
        #pragma unroll
        for (int j = 0; j < 4; j++) {
            glds16(Ab + (size_t)j * 8 * K + kt, As + (w * 32 + j * 8) * 64);
            glds16(Bb + (size_t)j * 8 * K + kt, Bs + (w * 32 + j * 8) * 64);
        }
        __syncthreads();
        #pragma unroll
        for (int kk = 0; kk < 2; kk++) {
            bf16x8 af[4], bfr[4];
            #pragma unroll
            for (int mi = 0; mi < 4; mi++) {
                int row = wr * 64 + mi * 16 + lr;
                int ch = (kk * 4 + lg) ^ (row & 7);
                af[mi] = *(const bf16x8*)(As + row * 64 + ch * 8);
            }
            #pragma unroll
            for (int ni = 0; ni < 4; ni++) {
                int row = wc * 64 + ni * 16 + lr;
                int ch = (kk * 4 + lg) ^ (row & 7);
                bfr[ni] = *(const bf16x8*)(Bs + row * 64 + ch * 8);
            }
            #pragma unroll
            for (int mi = 0; mi < 4; mi++)
                #pragma unroll
                for (int ni = 0; ni < 4; ni++)
                    acc[mi][ni] = __builtin_amdgcn_mfma_f32_16x16x32_bf16(
                        af[mi], bfr[ni], acc[mi][ni], 0, 0, 0);
        }
    }

    #pragma unroll
    for (int mi = 0; mi < 4; mi++) {
        #pragma unroll
        for (int ni = 0; ni < 4; ni++) {
            #pragma unroll
            for (int r = 0; r < 4; r++) {
                int gm = m0 + wr * 64 + mi * 16 + lg * 4 + r;
                int gn = n0 + wc * 64 + ni * 16 + lr;
                float v = acc[mi][ni][r];
                if (EPI == 0) {
                    Cbf[(size_t)gm * ldc + gn] = f2bf(v);
                } else if (EPI == 2) {
                    float g = v + bias[gn];
                    float a = bf2f(mul_src[(size_t)gm * ldc + gn]);
                    float sg = 1.f / (1.f + __expf(-g));
                    Cbf[(size_t)gm * ldc + gn] = f2bf(a * sg);
                } else {
                    Cf[(size_t)gm * ldc + gn] = v + bias[gn] + add_src[(size_t)gm * ldc + gn];
                }
            }
        }
    }
}

// ---------------- qz (absorbs hsum2): reduce partials -> hm, then qsum, z ----------------
__global__ __launch_bounds__(256) void qz_kernel(const float* __restrict__ part,
                                                 const u16* __restrict__ WqT,
                                                 const u16* __restrict__ WkT,
                                                 u16* __restrict__ z_bf) {
    int bh = blockIdx.x, b = bh >> 4, h = bh & 15;
    int tid = threadIdx.x;
    __shared__ float hm_l[1024];
    __shared__ float qs_l[64];
    __shared__ float red[256];
    {   // reduce 128 partial rows (L2-hot, 512 KB per block)
        const float4* src = (const float4*)(part + (size_t)b * 128 * 1024) + tid;
        float4 acc = {0.f, 0.f, 0.f, 0.f};
        for (int c = 0; c < 128; c++) {
            float4 v = src[c * 256];
            acc.x += v.x; acc.y += v.y; acc.z += v.z; acc.w += v.w;
        }
        const float inv = 1.f / 2048.f;
        acc.x *= inv; acc.y *= inv; acc.z *= inv; acc.w *= inv;
        ((float4*)hm_l)[tid] = acc;
    }
    __syncthreads();
    {
        int d = tid >> 2, q = tid & 3;
        const u16* wq = WqT + (size_t)(h * 64 + d) * 1024 + q * 256;
        float a = 0.f;
        for (int i = 0; i < 256; i += 8) {
            uint4 u = *(const uint4*)(wq + i);
            const u16* p = (const u16*)&u;
            #pragma unroll
            for (int j = 0; j < 8; j++) a += bf2f(p[j]) * hm_l[q * 256 + i + j];
        }
        red[tid] = a;
    }
    __syncthreads();
    if (tid < 64)
        qs_l[tid] = red[tid * 4] + red[tid * 4 + 1] + red[tid * 4 + 2] + red[tid * 4 + 3];
    __syncthreads();
    {
        float z0 = 0.f, z1 = 0.f, z2 = 0.f, z3 = 0.f;
        for (int d = 0; d < 64; d++) {
            float qs = qs_l[d];
            const u16* wk = WkT + (size_t)(h * 64 + d) * 1024 + tid * 4;
            uint2 u = *(const uint2*)wk;
            const u16* p = (const u16*)&u;
            z0 += qs * bf2f(p[0]); z1 += qs * bf2f(p[1]);
            z2 += qs * bf2f(p[2]); z3 += qs * bf2f(p[3]);
        }
        ushort4 o;
        o.x = f2bf(z0); o.y = f2bf(z1); o.z = f2bf(z2); o.w = f2bf(z3);
        *(ushort4*)(z_bf + (size_t)bh * 1024 + tid * 4) = o;
    }
}

// ---------------- score v3: barrier-free MFMA score over bf16 enc ----------------
__global__ __launch_bounds__(256) void score_kernel(const u16* __restrict__ ebf,
                                                    const u16* __restrict__ z_bf,
                                                    float* __restrict__ score) {
    const int b = blockIdx.y, kv0 = blockIdx.x * 64;
    const int tid = threadIdx.x, w = tid >> 6, l = tid & 63;
    const int lr = l & 15, lg = l >> 4;
    __shared__ u16 e_lds[2][64 * 64];   // 16 KB dbuf

    const u16* eb = ebf + (size_t)(b * 16384 + kv0) * 1024;
    const u16* zb = z_bf + (size_t)b * 16 * 1024;
    const int lrow = l >> 3, lch = l & 7;
    const int src_ch = lch ^ lrow;

    auto stage = [&](int kt, int buf) {
        const u16* s0 = eb + (size_t)(w * 16 + lrow) * 1024 + kt + src_ch * 8;
        glds16(s0,            e_lds[buf] + (w * 16) * 64);
        glds16(s0 + 8 * 1024, e_lds[buf] + (w * 16 + 8) * 64);
    };
    stage(0, 0);

    const f32x4 fz = {0.f, 0.f, 0.f, 0.f};
    f32x4 acc = fz;

    #pragma unroll 1
    for (int t = 0; t < 16; ++t) {
        const int kt = t * 64;
        if (t + 1 < 16) {
            stage(kt + 64, (t & 1) ^ 1);
            asm volatile("s_waitcnt vmcnt(2)" ::: "memory");
        } else {
            asm volatile("s_waitcnt vmcnt(0)" ::: "memory");
        }
        __builtin_amdgcn_sched_barrier(0);
        const u16* ecur = e_lds[t & 1];
        #pragma unroll
        for (int ks = 0; ks < 2; ks++) {
            bf16x8 af = *(const bf16x8*)(zb + (size_t)lr * 1024 + kt + ks * 32 + lg * 8);
            int row = w * 16 + lr;
            bf16x8 bf_ = *(const bf16x8*)(ecur + row * 64 + (((ks * 4 + lg) ^ (row & 7))) * 8);
            acc = __builtin_amdgcn_mfma_f32_16x16x32_bf16(af, bf_, acc, 0, 0, 0);
        }
    }
    #pragma unroll
    for (int r = 0; r < 4; r++)
        score[(size_t)(b * 16 + lg * 4 + r) * 16384 + kv0 + w * 16 + lr] = acc[r];
}

// ---------------- top-2048 select: 16-bit keys, single sweep, 1024 threads ----------------
__global__ __launch_bounds__(1024) void select_kernel(const float* __restrict__ score,
                                                      int* __restrict__ sel_idx) {
    const int bh = blockIdx.x;
    const float* sc = score + (size_t)bh * 16384;
    const int tid = threadIdx.x;
    const int grp = tid >> 8;

    __shared__ int hist[4][256];
    __shared__ int total[256];
    __shared__ int bc[4];

    u16 key[16];
    #pragma unroll
    for (int j = 0; j < 16; j++) {
        unsigned int b = __float_as_uint(sc[tid + j * 1024]);
        unsigned int ui = (b & 0x80000000u) ? ~b : (b | 0x80000000u);
        key[j] = (u16)(ui >> 16);
    }

    ((int*)hist)[tid] = 0;
    __syncthreads();
    #pragma unroll
    for (int j = 0; j < 16; j++) atomicAdd(&hist[grp][key[j] >> 8], 1);
    __syncthreads();
    if (tid < 256) total[tid] = hist[0][tid] + hist[1][tid] + hist[2][tid] + hist[3][tid];
    __syncthreads();
    if (tid == 0) {
        int want = 2048, acc = 0;
        for (int dd = 255; dd >= 0; dd--) {
            acc += total[dd];
            if (acc >= want) { bc[0] = dd; bc[1] = want - (acc - total[dd]); break; }
        }
    }
    __syncthreads();
    const int hi = bc[0];
    const int want1 = bc[1];

    ((int*)hist)[tid] = 0;
    __syncthreads();
    #pragma unroll
    for (int j = 0; j < 16; j++)
        if ((key[j] >> 8) == hi) atomicAdd(&hist[grp][key[j] & 0xff], 1);
    __syncthreads();
    if (tid < 256) total[tid] = hist[0][tid] + hist[1][tid] + hist[2][tid] + hist[3][tid];
    __syncthreads();
    if (tid == 0) {
        int want = want1, acc = 0;
        for (int dd = 255; dd >= 0; dd--) {
            acc += total[dd];
            if (acc >= want) { bc[0] = (hi << 8) | dd; bc[1] = want - (acc - total[dd]); break; }
        }
        bc[2] = 0; bc[3] = 0;
    }
    __syncthreads();
    const u16 thr = (u16)bc[0];
    const int n_eq = bc[1];
    const int base_eq = 2048 - n_eq;

    int* out = sel_idx + (size_t)bh * 2048;
    #pragma unroll
    for (int j = 0; j < 16; j++) {
        int i = tid + j * 1024;
        if (key[j] > thr) {
            int p = atomicAdd(&bc[2], 1);
            out[p] = i;
        } else if (key[j] == thr) {
            int p = atomicAdd(&bc[3], 1);
            if (p < n_eq) out[base_eq + p] = i;
        }
    }
}

// ---------------- selected projection (single-buffer): K_sel + V_selT(kappa) ----------------
__global__ __launch_bounds__(256) void selproj_kernel(const u16* __restrict__ ebf,
                                                      const u16* __restrict__ WkvT,
                                                      const int* __restrict__ sel_idx,
                                                      u16* __restrict__ k_sel,
                                                      u16* __restrict__ v_selT) {
    const int bh = blockIdx.y, b = bh >> 4, h = bh & 15;
    const int t0 = blockIdx.x * 128;
    const int tid = threadIdx.x, w = tid >> 6, l = tid & 63;
    const int lr = l & 15, lg = l >> 4;
    const int lane_row = l >> 3, src_ch = (l & 7) ^ lane_row;

    __shared__ u16 e_lds[128 * 64];
    __shared__ u16 w_lds[128 * 64];

    int encrow[4], wrow[4];
    #pragma unroll
    for (int j = 0; j < 4; j++) {
        int t = t0 + w * 32 + j * 8 + lane_row;
        encrow[j] = b * 16384 + sel_idx[(size_t)bh * 2048 + t];
        int r = w * 32 + j * 8 + lane_row;
        wrow[j] = (r < 64) ? (h * 64 + r) : (1024 + h * 64 + (r & 63));
    }

    const f32x4 fz = {0.f, 0.f, 0.f, 0.f};
    f32x4 acc_k[2][4], acc_v[8];
    #pragma unroll
    for (int i = 0; i < 2; i++)
        #pragma unroll
        for (int j = 0; j < 4; j++) acc_k[i][j] = fz;
    #pragma unroll
    for (int i = 0; i < 8; i++) acc_v[i] = fz;

    for (int kt = 0; kt < 1024; kt += 64) {
        __syncthreads();
        #pragma unroll
        for (int j = 0; j < 4; j++) {
            glds16(ebf + (size_t)encrow[j] * 1024 + kt + src_ch * 8, e_lds + (w * 32 + j * 8) * 64);
            glds16(WkvT + (size_t)wrow[j] * 1024 + kt + src_ch * 8, w_lds + (w * 32 + j * 8) * 64);
        }
        __syncthreads();
        #pragma unroll
        for (int ks = 0; ks < 2; ks++) {
            bf16x8 ae[2];
            #pragma unroll
            for (int mi = 0; mi < 2; mi++) {
                int row = w * 32 + mi * 16 + lr;
                ae[mi] = *(const bf16x8*)(e_lds + row * 64 + (((ks * 4 + lg) ^ (row & 7))) * 8);
            }
            bf16x8 aw;
            {
                int row = 64 + w * 16 + lr;
                aw = *(const bf16x8*)(w_lds + row * 64 + (((ks * 4 + lg) ^ (row & 7))) * 8);
            }
            #pragma unroll
            for (int ni = 0; ni < 4; ni++) {
                int row = ni * 16 + lr;
                bf16x8 bw = *(const bf16x8*)(w_lds + row * 64 + (((ks * 4 + lg) ^ (row & 7))) * 8);
                acc_k[0][ni] = __builtin_amdgcn_mfma_f32_16x16x32_bf16(ae[0], bw, acc_k[0][ni], 0, 0, 0);
                acc_k[1][ni] = __builtin_amdgcn_mfma_f32_16x16x32_bf16(ae[1], bw, acc_k[1][ni], 0, 0, 0);
            }
            #pragma unroll
            for (int ni = 0; ni < 8; ni++) {
                int row = ni * 16 + lr;
                bf16x8 be = *(const bf16x8*)(e_lds + row * 64 + (((ks * 4 + lg) ^ (row & 7))) * 8);
                acc_v[ni] = __builtin_amdgcn_mfma_f32_16x16x32_bf16(aw, be, acc_v[ni], 0, 0, 0);
            }
        }
    }

    u16* kb = k_sel + (size_t)bh * 2048 * 64;
    #pragma unroll
    for (int mi = 0; mi < 2; mi++)
        #pragma unroll
        for (int ni = 0; ni < 4; ni++)
            #pragma unroll
            for (int r = 0; r < 4; r++) {
                int t = t0 + w * 32 + mi * 16 + lg * 4 + r;
                int d = ni * 16 + lr;
                kb[(size_t)t * 64 + (((d >> 3) ^ (t & 7)) * 8) + (d & 7)] = f2bf(acc_k[mi][ni][r]);
            }
    u16* vb = v_selT + (size_t)bh * 64 * 2048;
    #pragma unroll
    for (int ni = 0; ni < 8; ni++)
        #pragma unroll
        for (int r = 0; r < 4; r++) {
            int d = w * 16 + lg * 4 + r;
            int t = t0 + ni * 16 + lr;
            int tl = t & 63;
            int kap = (tl & 15) * 4 + (tl >> 4);
            vb[(size_t)d * 2048 + (t & ~63) + (((kap >> 3) ^ (d & 7)) * 8) + (kap & 7)] =
                f2bf(acc_v[ni][r]);
        }
}

// ---------------- flash attention: 8 waves, QBLK=128, kappa-packed P store ----------------
__global__ __launch_bounds__(512) void attn_kernel(
    const u16* __restrict__ q_bf, const u16* __restrict__ k_sel,
    const u16* __restrict__ v_selT, u16* __restrict__ attn_out) {
    const int bh = blockIdx.y, b = bh >> 4, h = bh & 15;
    const int q0 = blockIdx.x * 128;
    const int tid = threadIdx.x, w = tid >> 6, l = tid & 63;
    const int lr = l & 15, lg = l >> 4;
    const int lk = lr & 7;
    const float SC = 0.18033688011f;   // 0.125 * log2(e)
    const float THR = 11.0f;

    __shared__ u16 k_lds[2][64 * 64];
    __shared__ u16 vt_lds[64 * 64];
    __shared__ u16 p_lds[8][16][68];

    const u16* qb = q_bf + ((size_t)b * 2048 + q0 + w * 16 + lr) * 1024 + h * 64;
    bf16x8 qf0 = *(const bf16x8*)(qb + lg * 8);
    bf16x8 qf1 = *(const bf16x8*)(qb + 32 + lg * 8);

    const f32x4 fz = {0.f, 0.f, 0.f, 0.f};
    f32x4 o[4];
    #pragma unroll
    for (int f = 0; f < 4; f++) o[f] = fz;
    float mm = -1e30f;
    float l_part[4] = {0.f, 0.f, 0.f, 0.f};

    const u16* kb  = k_sel + (size_t)bh * 2048 * 64;
    const u16* vtb = v_selT + (size_t)bh * 64 * 2048;

    auto stageK = [&](int it, int buf) {
        const u16* ksrc = kb + (size_t)(it * 64 + w * 8) * 64 + (size_t)l * 8;
        glds16(ksrc, k_lds[buf] + (w * 8) * 64);
    };
    auto stageV = [&](int it) {
        const u16* vsrc = vtb + (size_t)(w * 8 + (l >> 3)) * 2048 + it * 64 + (l & 7) * 8;
        glds16(vsrc, vt_lds + (w * 8) * 64);
    };

    stageK(0, 0);
    __syncthreads();

    #pragma unroll 1
    for (int it = 0; it < 32; ++it) {
        const int cur = it & 1;
        stageV(it);
        if (it + 1 < 32) stageK(it + 1, cur ^ 1);

        f32x4 s[4];
        #pragma unroll
        for (int c = 0; c < 4; c++) s[c] = fz;
        __builtin_amdgcn_s_setprio(1);
        #pragma unroll
        for (int c = 0; c < 4; c++) {
            const u16* krow = k_lds[cur] + (c * 16 + lr) * 64;
            bf16x8 kf0 = *(const bf16x8*)(krow + (lg ^ lk) * 8);
            s[c] = __builtin_amdgcn_mfma_f32_16x16x32_bf16(qf0, kf0, s[c], 0, 0, 0);
            bf16x8 kf1 = *(const bf16x8*)(krow + (((4 + lg) ^ lk)) * 8);
            s[c] = __builtin_amdgcn_mfma_f32_16x16x32_bf16(qf1, kf1, s[c], 0, 0, 0);
        }
        __builtin_amdgcn_s_setprio(0);

        float mx = s[0][0];
        #pragma unroll
        for (int c = 0; c < 4; c++)
            #pragma unroll
            for (int r = 0; r < 4; r++) mx = fmaxf(mx, s[c][r]);
        mx = fmaxf(mx, __shfl_xor(mx, 1));
        mx = fmaxf(mx, __shfl_xor(mx, 2));
        mx = fmaxf(mx, __shfl_xor(mx, 4));
        mx = fmaxf(mx, __shfl_xor(mx, 8));
        mx = fmaxf(mx, __shfl_xor(mx, 16));
        mx = fmaxf(mx, __shfl_xor(mx, 32));
        mx *= SC;
        if (mx > mm + THR) {
            float al = __builtin_amdgcn_exp2f(mm - mx);
            mm = mx;
            #pragma unroll
            for (int r = 0; r < 4; r++) l_part[r] *= al;
            #pragma unroll
            for (int f = 0; f < 4; f++)
                #pragma unroll
                for (int r = 0; r < 4; r++) o[f][r] *= al;
        }
        #pragma unroll
        for (int r = 0; r < 4; r++) {
            ushort4 pk;
            u16 pb[4];
            #pragma unroll
            for (int c = 0; c < 4; c++) {
                float p = __builtin_amdgcn_exp2f(__builtin_fmaf(s[c][r], SC, -mm));
                l_part[r] += p;
                __bf16 hv = (__bf16)p;
                pb[c] = *(u16*)&hv;
            }
            pk.x = pb[0]; pk.y = pb[1]; pk.z = pb[2]; pk.w = pb[3];
            *(ushort4*)(&p_lds[w][lg * 4 + r][lr * 4]) = pk;
        }

        if (it + 1 < 32) {
            asm volatile("s_waitcnt vmcnt(1)" ::: "memory");
        } else {
            asm volatile("s_waitcnt vmcnt(0)" ::: "memory");
        }
        __builtin_amdgcn_sched_barrier(0);
        __builtin_amdgcn_s_barrier();

        __builtin_amdgcn_s_setprio(1);
        #pragma unroll
        for (int kk = 0; kk < 2; kk++) {
            bf16x8 ap = *(const bf16x8*)(&p_lds[w][lr][kk * 32 + lg * 8]);
            #pragma unroll
            for (int f = 0; f < 4; f++) {
                const u16* vrow = vt_lds + (f * 16 + lr) * 64;
                bf16x8 bv = *(const bf16x8*)(vrow + (((kk * 4 + lg) ^ lk)) * 8);
                o[f] = __builtin_amdgcn_mfma_f32_16x16x32_bf16(ap, bv, o[f], 0, 0, 0);
            }
        }
        __builtin_amdgcn_s_setprio(0);

        __syncthreads();
    }

    float invl[4];
    #pragma unroll
    for (int r = 0; r < 4; r++) {
        float lr_ = l_part[r];
        lr_ += __shfl_xor(lr_, 1);
        lr_ += __shfl_xor(lr_, 2);
        lr_ += __shfl_xor(lr_, 4);
        lr_ += __shfl_xor(lr_, 8);
        invl[r] = 1.f / lr_;
    }
    u16* ob = attn_out + ((size_t)b * 2048 + q0 + w * 16 + lg * 4) * 1024 + h * 64 + lr;
    #pragma unroll
    for (int f = 0; f < 4; f++) {
        #pragma unroll
        for (int r = 0; r < 4; r++) {
            __bf16 hv = (__bf16)(o[f][r] * invl[r]);
            ob[(size_t)r * 1024 + f * 16] = *(u16*)&hv;
        }
    }
}

// ---------------- launcher ----------------
extern "C" void kernel_launch(void* const* d_in, const int* in_sizes, int n_in,
                              void* d_out, int out_size, void* d_ws, size_t ws_size,
                              hipStream_t stream) {
    const float* hidden = (const float*)d_in[0];
    const float* enc    = (const float*)d_in[1];
    const float* Wq = (const float*)d_in[2];
    const float* Wk = (const float*)d_in[3];
    const float* Wv = (const float*)d_in[4];
    const float* Wo = (const float*)d_in[5];
    const float* bo = (const float*)d_in[6];
    const float* Wg = (const float*)d_in[7];
    const float* bg = (const float*)d_in[8];
    float* out = (float*)d_out;

    char* ws = (char*)d_ws;
    size_t off = 0;
    auto alloc = [&](size_t bytes) -> char* {
        char* p = ws + off;
        off += (bytes + 255) & ~(size_t)255;
        return p;
    };
    u16* hbf   = (u16*)alloc(4096ull * 1024 * 2);
    u16* ebf   = (u16*)alloc(32768ull * 1024 * 2);
    u16* WqT   = (u16*)alloc(1024ull * 1024 * 2);
    u16* WkvT  = (u16*)alloc(2048ull * 1024 * 2);
    u16* WgT   = (u16*)alloc(1024ull * 1024 * 2);
    u16* WoT   = (u16*)alloc(1024ull * 1024 * 2);
    u16* q_bf  = (u16*)alloc(4096ull * 1024 * 2);
    float* part = (float*)alloc(2ull * 128 * 1024 * 4);
    u16* z_bf  = (u16*)alloc(32ull * 1024 * 2);
    float* scor = (float*)alloc(32ull * 16384 * 4);
    int* sel    = (int*)alloc(32ull * 2048 * 4);
    u16* ksel   = (u16*)alloc(32ull * 2048 * 64 * 2);
    u16* vT     = (u16*)alloc(32ull * 64 * 2048 * 2);
    u16* attn   = (u16*)alloc(4096ull * 1024 * 2);
    u16* gate   = (u16*)alloc(4096ull * 1024 * 2);
    (void)ws_size; (void)in_sizes; (void)n_in; (void)out_size;

    prep_kernel<<<dim3(2, 128), 256, 0, stream>>>(hidden, hbf, part);
    cast_bf16_kernel<<<32768, 256, 0, stream>>>(enc, ebf, 8388608);
    transpose_cast_kernel<<<dim3(32, 32, 5), dim3(32, 8), 0, stream>>>(
        Wq, Wk, Wv, Wg, Wo, WqT, WkvT, WgT, WoT);

    qz_kernel<<<32, 256, 0, stream>>>(part, WqT, WkvT, z_bf);
    score_kernel<<<dim3(256, 2), 256, 0, stream>>>(ebf, z_bf, scor);
    select_kernel<<<32, 1024, 0, stream>>>(scor, sel);
    selproj_kernel<<<dim3(16, 32), 256, 0, stream>>>(ebf, WkvT, sel, ksel, vT);

    gemm_bf16<0><<<dim3(8, 32), 256, 0, stream>>>(hbf, WqT, 1024, q_bf, nullptr, nullptr, nullptr, nullptr);
    attn_kernel<<<dim3(16, 32), 512, 0, stream>>>(q_bf, ksel, vT, attn);

    gemm_bf16<2><<<dim3(8, 32), 256, 0, stream>>>(attn, WgT, 1024, gate, bg, attn, nullptr, nullptr);
    gemm_bf16<3><<<dim3(8, 32), 256, 0, stream>>>(gate, WoT, 1024, nullptr, bo, nullptr, hidden, out);
}

// Round 15
// 237.510 us; speedup vs baseline: 1.0650x; 1.0506x over previous
//
#include <hip/hip_runtime.h>
#include <hip/hip_bf16.h>

typedef unsigned short u16;
typedef __bf16 bf16x8 __attribute__((ext_vector_type(8)));
typedef float f32x4 __attribute__((ext_vector_type(4)));

__device__ __forceinline__ u16 f2bf(float f) {
    union { float f; unsigned int u; } v; v.f = f;
    unsigned int u = v.u;
    unsigned int r = (u + 0x7fffu + ((u >> 16) & 1u)) >> 16;
    return (u16)r;
}
__device__ __forceinline__ float bf2f(u16 b) {
    union { unsigned int u; float f; } v; v.u = ((unsigned int)b) << 16;
    return v.f;
}

__device__ __forceinline__ void glds16(const u16* g, u16* l) {
    __builtin_amdgcn_global_load_lds(
        (__attribute__((address_space(1))) void*)(g),
        (__attribute__((address_space(3))) void*)(l), 16, 0, 0);
}

// ---------------- cast fp32 -> bf16 (enc) ----------------
__global__ __launch_bounds__(256) void cast_bf16_kernel(const float* __restrict__ src,
                                                        u16* __restrict__ dst, int n4) {
    int i = blockIdx.x * 256 + threadIdx.x;
    if (i >= n4) return;
    float4 v = ((const float4*)src)[i];
    ushort4 o;
    o.x = f2bf(v.x); o.y = f2bf(v.y); o.z = f2bf(v.z); o.w = f2bf(v.w);
    ((ushort4*)dst)[i] = o;
}

// ---------------- prep: fused hidden cast + column partial sums ----------------
__global__ __launch_bounds__(256) void prep_kernel(const float* __restrict__ hidden,
                                                   u16* __restrict__ hbf,
                                                   float* __restrict__ part) {
    int b = blockIdx.x, chunk = blockIdx.y;   // (2, 128)
    int tid = threadIdx.x;
    const float4* src = (const float4*)(hidden + ((size_t)b * 2048 + chunk * 16) * 1024) + tid;
    u16* dst = hbf + ((size_t)b * 2048 + chunk * 16) * 1024 + tid * 4;
    float4 acc = {0.f, 0.f, 0.f, 0.f};
    #pragma unroll
    for (int r = 0; r < 16; r++) {
        float4 v = src[r * 256];
        acc.x += v.x; acc.y += v.y; acc.z += v.z; acc.w += v.w;
        ushort4 o;
        o.x = f2bf(v.x); o.y = f2bf(v.y); o.z = f2bf(v.z); o.w = f2bf(v.w);
        *(ushort4*)(dst + (size_t)r * 1024) = o;
    }
    ((float4*)(part + ((size_t)b * 128 + chunk) * 1024))[tid] = acc;
}

// ---------------- transpose+cast weights: WT[n][k] = W[k][n] ----------------
__global__ __launch_bounds__(256) void transpose_cast_kernel(
    const float* __restrict__ Wq, const float* __restrict__ Wk, const float* __restrict__ Wv,
    const float* __restrict__ Wg, const float* __restrict__ Wo,
    u16* __restrict__ WqT, u16* __restrict__ WkvT, u16* __restrict__ WgT, u16* __restrict__ WoT) {
    __shared__ float tile[32][33];
    const float* src; u16* dst;
    switch (blockIdx.z) {
        case 0: src = Wq; dst = WqT; break;
        case 1: src = Wk; dst = WkvT; break;
        case 2: src = Wv; dst = WkvT + (size_t)1024 * 1024; break;
        case 3: src = Wg; dst = WgT; break;
        default: src = Wo; dst = WoT; break;
    }
    int n0 = blockIdx.x * 32, k0 = blockIdx.y * 32;
    int tx = threadIdx.x, ty = threadIdx.y;   // (32, 8)
    #pragma unroll
    for (int j = 0; j < 4; j++)
        tile[ty + j * 8][tx] = src[(size_t)(k0 + ty + j * 8) * 1024 + n0 + tx];
    __syncthreads();
    #pragma unroll
    for (int j = 0; j < 4; j++)
        dst[(size_t)(n0 + ty + j * 8) * 1024 + k0 + tx] = f2bf(tile[tx][ty + j * 8]);
}

// ---------------- 128M x 64N bf16 MFMA GEMM (2 blocks/CU) ----------------
// C[M,N] = A[M,1024] @ B[N,1024]^T. 4 waves (2Mx2N), per-wave 64x32.
template <int EPI>
__global__ __launch_bounds__(256) void gemm_bf16(
    const u16* __restrict__ A, const u16* __restrict__ B, int ldc,
    u16* __restrict__ Cbf, const float* __restrict__ bias,
    const u16* __restrict__ mul_src, const float* __restrict__ add_src,
    float* __restrict__ Cf) {
    constexpr int K = 1024;
    const int tid = threadIdx.x;
    const int w = tid >> 6, l = tid & 63;
    const int lr = l & 15, lg = l >> 4;
    const int wr = w >> 1, wc = w & 1;
    const int m0 = blockIdx.y * 128, n0 = blockIdx.x * 64;

    __shared__ u16 As[128 * 64];   // 16 KB
    __shared__ u16 Bs[64 * 64];    // 8 KB

    const f32x4 fz = {0.f, 0.f, 0.f, 0.f};
    f32x4 acc[4][2];
    #pragma unroll
    for (int i = 0; i < 4; i++)
        #pragma unroll
        for (int j = 0; j < 2; j++) acc[i][j] = fz;

    const int lane_row = l >> 3;
    const int lane_sl  = l & 7;
    const int src_ch   = lane_sl ^ lane_row;
    const u16* Ab = A + (size_t)(m0 + w * 32 + lane_row) * K + src_ch * 8;
    const u16* Bb = B + (size_t)(n0 + w * 16 + lane_row) * K + src_ch * 8;

    for (int kt = 0; kt < K; kt += 64) {
        __syncthreads();
        #pragma unroll
        for (int j = 0; j < 4; j++)
            glds16(Ab + (size_t)j * 8 * K + kt, As + (w * 32 + j * 8) * 64);
        glds16(Bb + kt,               Bs + (w * 16) * 64);
        glds16(Bb + (size_t)8 * K + kt, Bs + (w * 16 + 8) * 64);
        __syncthreads();
        #pragma unroll
        for (int kk = 0; kk < 2; kk++) {
            bf16x8 af[4], bfr[2];
            #pragma unroll
            for (int mi = 0; mi < 4; mi++) {
                int row = wr * 64 + mi * 16 + lr;
                int ch = (kk * 4 + lg) ^ (row & 7);
                af[mi] = *(const bf16x8*)(As + row * 64 + ch * 8);
            }
            #pragma unroll
            for (int ni = 0; ni < 2; ni++) {
                int row = wc * 32 + ni * 16 + lr;
                int ch = (kk * 4 + lg) ^ (row & 7);
                bfr[ni] = *(const bf16x8*)(Bs + row * 64 + ch * 8);
            }
            #pragma unroll
            for (int mi = 0; mi < 4; mi++)
                #pragma unroll
                for (int ni = 0; ni < 2; ni++)
                    acc[mi][ni] = __builtin_amdgcn_mfma_f32_16x16x32_bf16(
                        af[mi], bfr[ni], acc[mi][ni], 0, 0, 0);
        }
    }

    #pragma unroll
    for (int mi = 0; mi < 4; mi++) {
        #pragma unroll
        for (int ni = 0; ni < 2; ni++) {
            #pragma unroll
            for (int r = 0; r < 4; r++) {
                int gm = m0 + wr * 64 + mi * 16 + lg * 4 + r;
                int gn = n0 + wc * 32 + ni * 16 + lr;
                float v = acc[mi][ni][r];
                if (EPI == 0) {
                    Cbf[(size_t)gm * ldc + gn] = f2bf(v);
                } else if (EPI == 2) {
                    float g = v + bias[gn];
                    float a = bf2f(mul_src[(size_t)gm * ldc + gn]);
                    float sg = 1.f / (1.f + __expf(-g));
                    Cbf[(size_t)gm * ldc + gn] = f2bf(a * sg);
                } else {
                    Cf[(size_t)gm * ldc + gn] = v + bias[gn] + add_src[(size_t)gm * ldc + gn];
                }
            }
        }
    }
}

// ---------------- qz (absorbs hsum2) ----------------
__global__ __launch_bounds__(256) void qz_kernel(const float* __restrict__ part,
                                                 const u16* __restrict__ WqT,
                                                 const u16* __restrict__ WkT,
                                                 u16* __restrict__ z_bf) {
    int bh = blockIdx.x, b = bh >> 4, h = bh & 15;
    int tid = threadIdx.x;
    __shared__ float hm_l[1024];
    __shared__ float qs_l[64];
    __shared__ float red[256];
    {
        const float4* src = (const float4*)(part + (size_t)b * 128 * 1024) + tid;
        float4 acc = {0.f, 0.f, 0.f, 0.f};
        for (int c = 0; c < 128; c++) {
            float4 v = src[c * 256];
            acc.x += v.x; acc.y += v.y; acc.z += v.z; acc.w += v.w;
        }
        const float inv = 1.f / 2048.f;
        acc.x *= inv; acc.y *= inv; acc.z *= inv; acc.w *= inv;
        ((float4*)hm_l)[tid] = acc;
    }
    __syncthreads();
    {
        int d = tid >> 2, q = tid & 3;
        const u16* wq = WqT + (size_t)(h * 64 + d) * 1024 + q * 256;
        float a = 0.f;
        for (int i = 0; i < 256; i += 8) {
            uint4 u = *(const uint4*)(wq + i);
            const u16* p = (const u16*)&u;
            #pragma unroll
            for (int j = 0; j < 8; j++) a += bf2f(p[j]) * hm_l[q * 256 + i + j];
        }
        red[tid] = a;
    }
    __syncthreads();
    if (tid < 64)
        qs_l[tid] = red[tid * 4] + red[tid * 4 + 1] + red[tid * 4 + 2] + red[tid * 4 + 3];
    __syncthreads();
    {
        float z0 = 0.f, z1 = 0.f, z2 = 0.f, z3 = 0.f;
        for (int d = 0; d < 64; d++) {
            float qs = qs_l[d];
            const u16* wk = WkT + (size_t)(h * 64 + d) * 1024 + tid * 4;
            uint2 u = *(const uint2*)wk;
            const u16* p = (const u16*)&u;
            z0 += qs * bf2f(p[0]); z1 += qs * bf2f(p[1]);
            z2 += qs * bf2f(p[2]); z3 += qs * bf2f(p[3]);
        }
        ushort4 o;
        o.x = f2bf(z0); o.y = f2bf(z1); o.z = f2bf(z2); o.w = f2bf(z3);
        *(ushort4*)(z_bf + (size_t)bh * 1024 + tid * 4) = o;
    }
}

// ---------------- score v3: barrier-free MFMA score over bf16 enc ----------------
__global__ __launch_bounds__(256) void score_kernel(const u16* __restrict__ ebf,
                                                    const u16* __restrict__ z_bf,
                                                    float* __restrict__ score) {
    const int b = blockIdx.y, kv0 = blockIdx.x * 64;
    const int tid = threadIdx.x, w = tid >> 6, l = tid & 63;
    const int lr = l & 15, lg = l >> 4;
    __shared__ u16 e_lds[2][64 * 64];

    const u16* eb = ebf + (size_t)(b * 16384 + kv0) * 1024;
    const u16* zb = z_bf + (size_t)b * 16 * 1024;
    const int lrow = l >> 3, lch = l & 7;
    const int src_ch = lch ^ lrow;

    auto stage = [&](int kt, int buf) {
        const u16* s0 = eb + (size_t)(w * 16 + lrow) * 1024 + kt + src_ch * 8;
        glds16(s0,            e_lds[buf] + (w * 16) * 64);
        glds16(s0 + 8 * 1024, e_lds[buf] + (w * 16 + 8) * 64);
    };
    stage(0, 0);

    const f32x4 fz = {0.f, 0.f, 0.f, 0.f};
    f32x4 acc = fz;

    #pragma unroll 1
    for (int t = 0; t < 16; ++t) {
        const int kt = t * 64;
        if (t + 1 < 16) {
            stage(kt + 64, (t & 1) ^ 1);
            asm volatile("s_waitcnt vmcnt(2)" ::: "memory");
        } else {
            asm volatile("s_waitcnt vmcnt(0)" ::: "memory");
        }
        __builtin_amdgcn_sched_barrier(0);
        const u16* ecur = e_lds[t & 1];
        #pragma unroll
        for (int ks = 0; ks < 2; ks++) {
            bf16x8 af = *(const bf16x8*)(zb + (size_t)lr * 1024 + kt + ks * 32 + lg * 8);
            int row = w * 16 + lr;
            bf16x8 bf_ = *(const bf16x8*)(ecur + row * 64 + (((ks * 4 + lg) ^ (row & 7))) * 8);
            acc = __builtin_amdgcn_mfma_f32_16x16x32_bf16(af, bf_, acc, 0, 0, 0);
        }
    }
    #pragma unroll
    for (int r = 0; r < 4; r++)
        score[(size_t)(b * 16 + lg * 4 + r) * 16384 + kv0 + w * 16 + lr] = acc[r];
}

// ---------------- top-2048 select: 16-bit keys, single sweep, 1024 threads ----------------
__global__ __launch_bounds__(1024) void select_kernel(const float* __restrict__ score,
                                                      int* __restrict__ sel_idx) {
    const int bh = blockIdx.x;
    const float* sc = score + (size_t)bh * 16384;
    const int tid = threadIdx.x;
    const int grp = tid >> 8;

    __shared__ int hist[4][256];
    __shared__ int total[256];
    __shared__ int bc[4];

    u16 key[16];
    #pragma unroll
    for (int j = 0; j < 16; j++) {
        unsigned int b = __float_as_uint(sc[tid + j * 1024]);
        unsigned int ui = (b & 0x80000000u) ? ~b : (b | 0x80000000u);
        key[j] = (u16)(ui >> 16);
    }

    ((int*)hist)[tid] = 0;
    __syncthreads();
    #pragma unroll
    for (int j = 0; j < 16; j++) atomicAdd(&hist[grp][key[j] >> 8], 1);
    __syncthreads();
    if (tid < 256) total[tid] = hist[0][tid] + hist[1][tid] + hist[2][tid] + hist[3][tid];
    __syncthreads();
    if (tid == 0) {
        int want = 2048, acc = 0;
        for (int dd = 255; dd >= 0; dd--) {
            acc += total[dd];
            if (acc >= want) { bc[0] = dd; bc[1] = want - (acc - total[dd]); break; }
        }
    }
    __syncthreads();
    const int hi = bc[0];
    const int want1 = bc[1];

    ((int*)hist)[tid] = 0;
    __syncthreads();
    #pragma unroll
    for (int j = 0; j < 16; j++)
        if ((key[j] >> 8) == hi) atomicAdd(&hist[grp][key[j] & 0xff], 1);
    __syncthreads();
    if (tid < 256) total[tid] = hist[0][tid] + hist[1][tid] + hist[2][tid] + hist[3][tid];
    __syncthreads();
    if (tid == 0) {
        int want = want1, acc = 0;
        for (int dd = 255; dd >= 0; dd--) {
            acc += total[dd];
            if (acc >= want) { bc[0] = (hi << 8) | dd; bc[1] = want - (acc - total[dd]); break; }
        }
        bc[2] = 0; bc[3] = 0;
    }
    __syncthreads();
    const u16 thr = (u16)bc[0];
    const int n_eq = bc[1];
    const int base_eq = 2048 - n_eq;

    int* out = sel_idx + (size_t)bh * 2048;
    #pragma unroll
    for (int j = 0; j < 16; j++) {
        int i = tid + j * 1024;
        if (key[j] > thr) {
            int p = atomicAdd(&bc[2], 1);
            out[p] = i;
        } else if (key[j] == thr) {
            int p = atomicAdd(&bc[3], 1);
            if (p < n_eq) out[base_eq + p] = i;
        }
    }
}

// ---------------- selected projection (single-buffer): K_sel + V_selT(kappa) ----------------
__global__ __launch_bounds__(256) void selproj_kernel(const u16* __restrict__ ebf,
                                                      const u16* __restrict__ WkvT,
                                                      const int* __restrict__ sel_idx,
                                                      u16* __restrict__ k_sel,
                                                      u16* __restrict__ v_selT) {
    const int bh = blockIdx.y, b = bh >> 4, h = bh & 15;
    const int t0 = blockIdx.x * 128;
    const int tid = threadIdx.x, w = tid >> 6, l = tid & 63;
    const int lr = l & 15, lg = l >> 4;
    const int lane_row = l >> 3, src_ch = (l & 7) ^ lane_row;

    __shared__ u16 e_lds[128 * 64];
    __shared__ u16 w_lds[128 * 64];

    int encrow[4], wrow[4];
    #pragma unroll
    for (int j = 0; j < 4; j++) {
        int t = t0 + w * 32 + j * 8 + lane_row;
        encrow[j] = b * 16384 + sel_idx[(size_t)bh * 2048 + t];
        int r = w * 32 + j * 8 + lane_row;
        wrow[j] = (r < 64) ? (h * 64 + r) : (1024 + h * 64 + (r & 63));
    }

    const f32x4 fz = {0.f, 0.f, 0.f, 0.f};
    f32x4 acc_k[2][4], acc_v[8];
    #pragma unroll
    for (int i = 0; i < 2; i++)
        #pragma unroll
        for (int j = 0; j < 4; j++) acc_k[i][j] = fz;
    #pragma unroll
    for (int i = 0; i < 8; i++) acc_v[i] = fz;

    for (int kt = 0; kt < 1024; kt += 64) {
        __syncthreads();
        #pragma unroll
        for (int j = 0; j < 4; j++) {
            glds16(ebf + (size_t)encrow[j] * 1024 + kt + src_ch * 8, e_lds + (w * 32 + j * 8) * 64);
            glds16(WkvT + (size_t)wrow[j] * 1024 + kt + src_ch * 8, w_lds + (w * 32 + j * 8) * 64);
        }
        __syncthreads();
        #pragma unroll
        for (int ks = 0; ks < 2; ks++) {
            bf16x8 ae[2];
            #pragma unroll
            for (int mi = 0; mi < 2; mi++) {
                int row = w * 32 + mi * 16 + lr;
                ae[mi] = *(const bf16x8*)(e_lds + row * 64 + (((ks * 4 + lg) ^ (row & 7))) * 8);
            }
            bf16x8 aw;
            {
                int row = 64 + w * 16 + lr;
                aw = *(const bf16x8*)(w_lds + row * 64 + (((ks * 4 + lg) ^ (row & 7))) * 8);
            }
            #pragma unroll
            for (int ni = 0; ni < 4; ni++) {
                int row = ni * 16 + lr;
                bf16x8 bw = *(const bf16x8*)(w_lds + row * 64 + (((ks * 4 + lg) ^ (row & 7))) * 8);
                acc_k[0][ni] = __builtin_amdgcn_mfma_f32_16x16x32_bf16(ae[0], bw, acc_k[0][ni], 0, 0, 0);
                acc_k[1][ni] = __builtin_amdgcn_mfma_f32_16x16x32_bf16(ae[1], bw, acc_k[1][ni], 0, 0, 0);
            }
            #pragma unroll
            for (int ni = 0; ni < 8; ni++) {
                int row = ni * 16 + lr;
                bf16x8 be = *(const bf16x8*)(e_lds + row * 64 + (((ks * 4 + lg) ^ (row & 7))) * 8);
                acc_v[ni] = __builtin_amdgcn_mfma_f32_16x16x32_bf16(aw, be, acc_v[ni], 0, 0, 0);
            }
        }
    }

    u16* kb = k_sel + (size_t)bh * 2048 * 64;
    #pragma unroll
    for (int mi = 0; mi < 2; mi++)
        #pragma unroll
        for (int ni = 0; ni < 4; ni++)
            #pragma unroll
            for (int r = 0; r < 4; r++) {
                int t = t0 + w * 32 + mi * 16 + lg * 4 + r;
                int d = ni * 16 + lr;
                kb[(size_t)t * 64 + (((d >> 3) ^ (t & 7)) * 8) + (d & 7)] = f2bf(acc_k[mi][ni][r]);
            }
    u16* vb = v_selT + (size_t)bh * 64 * 2048;
    #pragma unroll
    for (int ni = 0; ni < 8; ni++)
        #pragma unroll
        for (int r = 0; r < 4; r++) {
            int d = w * 16 + lg * 4 + r;
            int t = t0 + ni * 16 + lr;
            int tl = t & 63;
            int kap = (tl & 15) * 4 + (tl >> 4);
            vb[(size_t)d * 2048 + (t & ~63) + (((kap >> 3) ^ (d & 7)) * 8) + (kap & 7)] =
                f2bf(acc_v[ni][r]);
        }
}

// ---------------- flash attention: 8 waves, QBLK=128, kappa-packed P store ----------------
__global__ __launch_bounds__(512) void attn_kernel(
    const u16* __restrict__ q_bf, const u16* __restrict__ k_sel,
    const u16* __restrict__ v_selT, u16* __restrict__ attn_out) {
    const int bh = blockIdx.y, b = bh >> 4, h = bh & 15;
    const int q0 = blockIdx.x * 128;
    const int tid = threadIdx.x, w = tid >> 6, l = tid & 63;
    const int lr = l & 15, lg = l >> 4;
    const int lk = lr & 7;
    const float SC = 0.18033688011f;   // 0.125 * log2(e)
    const float THR = 11.0f;

    __shared__ u16 k_lds[2][64 * 64];
    __shared__ u16 vt_lds[64 * 64];
    __shared__ u16 p_lds[8][16][68];

    const u16* qb = q_bf + ((size_t)b * 2048 + q0 + w * 16 + lr) * 1024 + h * 64;
    bf16x8 qf0 = *(const bf16x8*)(qb + lg * 8);
    bf16x8 qf1 = *(const bf16x8*)(qb + 32 + lg * 8);

    const f32x4 fz = {0.f, 0.f, 0.f, 0.f};
    f32x4 o[4];
    #pragma unroll
    for (int f = 0; f < 4; f++) o[f] = fz;
    float mm = -1e30f;
    float l_part[4] = {0.f, 0.f, 0.f, 0.f};

    const u16* kb  = k_sel + (size_t)bh * 2048 * 64;
    const u16* vtb = v_selT + (size_t)bh * 64 * 2048;

    auto stageK = [&](int it, int buf) {
        const u16* ksrc = kb + (size_t)(it * 64 + w * 8) * 64 + (size_t)l * 8;
        glds16(ksrc, k_lds[buf] + (w * 8) * 64);
    };
    auto stageV = [&](int it) {
        const u16* vsrc = vtb + (size_t)(w * 8 + (l >> 3)) * 2048 + it * 64 + (l & 7) * 8;
        glds16(vsrc, vt_lds + (w * 8) * 64);
    };

    stageK(0, 0);
    __syncthreads();

    #pragma unroll 1
    for (int it = 0; it < 32; ++it) {
        const int cur = it & 1;
        stageV(it);
        if (it + 1 < 32) stageK(it + 1, cur ^ 1);

        f32x4 s[4];
        #pragma unroll
        for (int c = 0; c < 4; c++) s[c] = fz;
        __builtin_amdgcn_s_setprio(1);
        #pragma unroll
        for (int c = 0; c < 4; c++) {
            const u16* krow = k_lds[cur] + (c * 16 + lr) * 64;
            bf16x8 kf0 = *(const bf16x8*)(krow + (lg ^ lk) * 8);
            s[c] = __builtin_amdgcn_mfma_f32_16x16x32_bf16(qf0, kf0, s[c], 0, 0, 0);
            bf16x8 kf1 = *(const bf16x8*)(krow + (((4 + lg) ^ lk)) * 8);
            s[c] = __builtin_amdgcn_mfma_f32_16x16x32_bf16(qf1, kf1, s[c], 0, 0, 0);
        }
        __builtin_amdgcn_s_setprio(0);

        float mx = s[0][0];
        #pragma unroll
        for (int c = 0; c < 4; c++)
            #pragma unroll
            for (int r = 0; r < 4; r++) mx = fmaxf(mx, s[c][r]);
        mx = fmaxf(mx, __shfl_xor(mx, 1));
        mx = fmaxf(mx, __shfl_xor(mx, 2));
        mx = fmaxf(mx, __shfl_xor(mx, 4));
        mx = fmaxf(mx, __shfl_xor(mx, 8));
        mx = fmaxf(mx, __shfl_xor(mx, 16));
        mx = fmaxf(mx, __shfl_xor(mx, 32));
        mx *= SC;
        if (mx > mm + THR) {
            float al = __builtin_amdgcn_exp2f(mm - mx);
            mm = mx;
            #pragma unroll
            for (int r = 0; r < 4; r++) l_part[r] *= al;
            #pragma unroll
            for (int f = 0; f < 4; f++)
                #pragma unroll
                for (int r = 0; r < 4; r++) o[f][r] *= al;
        }
        #pragma unroll
        for (int r = 0; r < 4; r++) {
            ushort4 pk;
            u16 pb[4];
            #pragma unroll
            for (int c = 0; c < 4; c++) {
                float p = __builtin_amdgcn_exp2f(__builtin_fmaf(s[c][r], SC, -mm));
                l_part[r] += p;
                __bf16 hv = (__bf16)p;
                pb[c] = *(u16*)&hv;
            }
            pk.x = pb[0]; pk.y = pb[1]; pk.z = pb[2]; pk.w = pb[3];
            *(ushort4*)(&p_lds[w][lg * 4 + r][lr * 4]) = pk;
        }

        if (it + 1 < 32) {
            asm volatile("s_waitcnt vmcnt(1)" ::: "memory");
        } else {
            asm volatile("s_waitcnt vmcnt(0)" ::: "memory");
        }
        __builtin_amdgcn_sched_barrier(0);
        __builtin_amdgcn_s_barrier();

        __builtin_amdgcn_s_setprio(1);
        #pragma unroll
        for (int kk = 0; kk < 2; kk++) {
            bf16x8 ap = *(const bf16x8*)(&p_lds[w][lr][kk * 32 + lg * 8]);
            #pragma unroll
            for (int f = 0; f < 4; f++) {
                const u16* vrow = vt_lds + (f * 16 + lr) * 64;
                bf16x8 bv = *(const bf16x8*)(vrow + (((kk * 4 + lg) ^ lk)) * 8);
                o[f] = __builtin_amdgcn_mfma_f32_16x16x32_bf16(ap, bv, o[f], 0, 0, 0);
            }
        }
        __builtin_amdgcn_s_setprio(0);

        __syncthreads();
    }

    float invl[4];
    #pragma unroll
    for (int r = 0; r < 4; r++) {
        float lr_ = l_part[r];
        lr_ += __shfl_xor(lr_, 1);
        lr_ += __shfl_xor(lr_, 2);
        lr_ += __shfl_xor(lr_, 4);
        lr_ += __shfl_xor(lr_, 8);
        invl[r] = 1.f / lr_;
    }
    u16* ob = attn_out + ((size_t)b * 2048 + q0 + w * 16 + lg * 4) * 1024 + h * 64 + lr;
    #pragma unroll
    for (int f = 0; f < 4; f++) {
        #pragma unroll
        for (int r = 0; r < 4; r++) {
            __bf16 hv = (__bf16)(o[f][r] * invl[r]);
            ob[(size_t)r * 1024 + f * 16] = *(u16*)&hv;
        }
    }
}

// ---------------- launcher ----------------
extern "C" void kernel_launch(void* const* d_in, const int* in_sizes, int n_in,
                              void* d_out, int out_size, void* d_ws, size_t ws_size,
                              hipStream_t stream) {
    const float* hidden = (const float*)d_in[0];
    const float* enc    = (const float*)d_in[1];
    const float* Wq = (const float*)d_in[2];
    const float* Wk = (const float*)d_in[3];
    const float* Wv = (const float*)d_in[4];
    const float* Wo = (const float*)d_in[5];
    const float* bo = (const float*)d_in[6];
    const float* Wg = (const float*)d_in[7];
    const float* bg = (const float*)d_in[8];
    float* out = (float*)d_out;

    char* ws = (char*)d_ws;
    size_t off = 0;
    auto alloc = [&](size_t bytes) -> char* {
        char* p = ws + off;
        off += (bytes + 255) & ~(size_t)255;
        return p;
    };
    u16* hbf   = (u16*)alloc(4096ull * 1024 * 2);
    u16* ebf   = (u16*)alloc(32768ull * 1024 * 2);
    u16* WqT   = (u16*)alloc(1024ull * 1024 * 2);
    u16* WkvT  = (u16*)alloc(2048ull * 1024 * 2);
    u16* WgT   = (u16*)alloc(1024ull * 1024 * 2);
    u16* WoT   = (u16*)alloc(1024ull * 1024 * 2);
    u16* q_bf  = (u16*)alloc(4096ull * 1024 * 2);
    float* part = (float*)alloc(2ull * 128 * 1024 * 4);
    u16* z_bf  = (u16*)alloc(32ull * 1024 * 2);
    float* scor = (float*)alloc(32ull * 16384 * 4);
    int* sel    = (int*)alloc(32ull * 2048 * 4);
    u16* ksel   = (u16*)alloc(32ull * 2048 * 64 * 2);
    u16* vT     = (u16*)alloc(32ull * 64 * 2048 * 2);
    u16* attn   = (u16*)alloc(4096ull * 1024 * 2);
    u16* gate   = (u16*)alloc(4096ull * 1024 * 2);
    (void)ws_size; (void)in_sizes; (void)n_in; (void)out_size;

    prep_kernel<<<dim3(2, 128), 256, 0, stream>>>(hidden, hbf, part);
    cast_bf16_kernel<<<32768, 256, 0, stream>>>(enc, ebf, 8388608);
    transpose_cast_kernel<<<dim3(32, 32, 5), dim3(32, 8), 0, stream>>>(
        Wq, Wk, Wv, Wg, Wo, WqT, WkvT, WgT, WoT);

    qz_kernel<<<32, 256, 0, stream>>>(part, WqT, WkvT, z_bf);
    score_kernel<<<dim3(256, 2), 256, 0, stream>>>(ebf, z_bf, scor);
    select_kernel<<<32, 1024, 0, stream>>>(scor, sel);
    selproj_kernel<<<dim3(16, 32), 256, 0, stream>>>(ebf, WkvT, sel, ksel, vT);

    gemm_bf16<0><<<dim3(16, 32), 256, 0, stream>>>(hbf, WqT, 1024, q_bf, nullptr, nullptr, nullptr, nullptr);
    attn_kernel<<<dim3(16, 32), 512, 0, stream>>>(q_bf, ksel, vT, attn);

    gemm_bf16<2><<<dim3(16, 32), 256, 0, stream>>>(attn, WgT, 1024, gate, bg, attn, nullptr, nullptr);
    gemm_bf16<3><<<dim3(16, 32), 256, 0, stream>>>(gate, WoT, 1024, nullptr, bo, nullptr, hidden, out);
}

// Round 16
// 230.821 us; speedup vs baseline: 1.0959x; 1.0290x over previous
//
#include <hip/hip_runtime.h>
#include <hip/hip_bf16.h>

typedef unsigned short u16;
typedef __bf16 bf16x8 __attribute__((ext_vector_type(8)));
typedef float f32x4 __attribute__((ext_vector_type(4)));

__device__ __forceinline__ u16 f2bf(float f) {
    union { float f; unsigned int u; } v; v.f = f;
    unsigned int u = v.u;
    unsigned int r = (u + 0x7fffu + ((u >> 16) & 1u)) >> 16;
    return (u16)r;
}
__device__ __forceinline__ float bf2f(u16 b) {
    union { unsigned int u; float f; } v; v.u = ((unsigned int)b) << 16;
    return v.f;
}

__device__ __forceinline__ void glds16(const u16* g, u16* l) {
    __builtin_amdgcn_global_load_lds(
        (__attribute__((address_space(1))) void*)(g),
        (__attribute__((address_space(3))) void*)(l), 16, 0, 0);
}

// ---------------- prep: fused hidden cast + column partial sums ----------------
__global__ __launch_bounds__(256) void prep_kernel(const float* __restrict__ hidden,
                                                   u16* __restrict__ hbf,
                                                   float* __restrict__ part) {
    int b = blockIdx.x, chunk = blockIdx.y;   // (2, 128)
    int tid = threadIdx.x;
    const float4* src = (const float4*)(hidden + ((size_t)b * 2048 + chunk * 16) * 1024) + tid;
    u16* dst = hbf + ((size_t)b * 2048 + chunk * 16) * 1024 + tid * 4;
    float4 acc = {0.f, 0.f, 0.f, 0.f};
    #pragma unroll
    for (int r = 0; r < 16; r++) {
        float4 v = src[r * 256];
        acc.x += v.x; acc.y += v.y; acc.z += v.z; acc.w += v.w;
        ushort4 o;
        o.x = f2bf(v.x); o.y = f2bf(v.y); o.z = f2bf(v.z); o.w = f2bf(v.w);
        *(ushort4*)(dst + (size_t)r * 1024) = o;
    }
    ((float4*)(part + ((size_t)b * 128 + chunk) * 1024))[tid] = acc;
}

// ---------------- transpose+cast weights: WT[n][k] = W[k][n] ----------------
__global__ __launch_bounds__(256) void transpose_cast_kernel(
    const float* __restrict__ Wq, const float* __restrict__ Wk, const float* __restrict__ Wv,
    const float* __restrict__ Wg, const float* __restrict__ Wo,
    u16* __restrict__ WqT, u16* __restrict__ WkvT, u16* __restrict__ WgT, u16* __restrict__ WoT) {
    __shared__ float tile[32][33];
    const float* src; u16* dst;
    switch (blockIdx.z) {
        case 0: src = Wq; dst = WqT; break;
        case 1: src = Wk; dst = WkvT; break;
        case 2: src = Wv; dst = WkvT + (size_t)1024 * 1024; break;
        case 3: src = Wg; dst = WgT; break;
        default: src = Wo; dst = WoT; break;
    }
    int n0 = blockIdx.x * 32, k0 = blockIdx.y * 32;
    int tx = threadIdx.x, ty = threadIdx.y;   // (32, 8)
    #pragma unroll
    for (int j = 0; j < 4; j++)
        tile[ty + j * 8][tx] = src[(size_t)(k0 + ty + j * 8) * 1024 + n0 + tx];
    __syncthreads();
    #pragma unroll
    for (int j = 0; j < 4; j++)
        dst[(size_t)(n0 + ty + j * 8) * 1024 + k0 + tx] = f2bf(tile[tx][ty + j * 8]);
}

// ---------------- 128M x 64N bf16 MFMA GEMM (2 blocks/CU) ----------------
template <int EPI>
__global__ __launch_bounds__(256) void gemm_bf16(
    const u16* __restrict__ A, const u16* __restrict__ B, int ldc,
    u16* __restrict__ Cbf, const float* __restrict__ bias,
    const u16* __restrict__ mul_src, const float* __restrict__ add_src,
    float* __restrict__ Cf) {
    constexpr int K = 1024;
    const int tid = threadIdx.x;
    const int w = tid >> 6, l = tid & 63;
    const int lr = l & 15, lg = l >> 4;
    const int wr = w >> 1, wc = w & 1;
    const int m0 = blockIdx.y * 128, n0 = blockIdx.x * 64;

    __shared__ u16 As[128 * 64];
    __shared__ u16 Bs[64 * 64];

    const f32x4 fz = {0.f, 0.f, 0.f, 0.f};
    f32x4 acc[4][2];
    #pragma unroll
    for (int i = 0; i < 4; i++)
        #pragma unroll
        for (int j = 0; j < 2; j++) acc[i][j] = fz;

    const int lane_row = l >> 3;
    const int lane_sl  = l & 7;
    const int src_ch   = lane_sl ^ lane_row;
    const u16* Ab = A + (size_t)(m0 + w * 32 + lane_row) * K + src_ch * 8;
    const u16* Bb = B + (size_t)(n0 + w * 16 + lane_row) * K + src_ch * 8;

    for (int kt = 0; kt < K; kt += 64) {
        __syncthreads();
        #pragma unroll
        for (int j = 0; j < 4; j++)
            glds16(Ab + (size_t)j * 8 * K + kt, As + (w * 32 + j * 8) * 64);
        glds16(Bb + kt,               Bs + (w * 16) * 64);
        glds16(Bb + (size_t)8 * K + kt, Bs + (w * 16 + 8) * 64);
        __syncthreads();
        #pragma unroll
        for (int kk = 0; kk < 2; kk++) {
            bf16x8 af[4], bfr[2];
            #pragma unroll
            for (int mi = 0; mi < 4; mi++) {
                int row = wr * 64 + mi * 16 + lr;
                int ch = (kk * 4 + lg) ^ (row & 7);
                af[mi] = *(const bf16x8*)(As + row * 64 + ch * 8);
            }
            #pragma unroll
            for (int ni = 0; ni < 2; ni++) {
                int row = wc * 32 + ni * 16 + lr;
                int ch = (kk * 4 + lg) ^ (row & 7);
                bfr[ni] = *(const bf16x8*)(Bs + row * 64 + ch * 8);
            }
            #pragma unroll
            for (int mi = 0; mi < 4; mi++)
                #pragma unroll
                for (int ni = 0; ni < 2; ni++)
                    acc[mi][ni] = __builtin_amdgcn_mfma_f32_16x16x32_bf16(
                        af[mi], bfr[ni], acc[mi][ni], 0, 0, 0);
        }
    }

    #pragma unroll
    for (int mi = 0; mi < 4; mi++) {
        #pragma unroll
        for (int ni = 0; ni < 2; ni++) {
            #pragma unroll
            for (int r = 0; r < 4; r++) {
                int gm = m0 + wr * 64 + mi * 16 + lg * 4 + r;
                int gn = n0 + wc * 32 + ni * 16 + lr;
                float v = acc[mi][ni][r];
                if (EPI == 0) {
                    Cbf[(size_t)gm * ldc + gn] = f2bf(v);
                } else if (EPI == 2) {
                    float g = v + bias[gn];
                    float a = bf2f(mul_src[(size_t)gm * ldc + gn]);
                    float sg = 1.f / (1.f + __expf(-g));
                    Cbf[(size_t)gm * ldc + gn] = f2bf(a * sg);
                } else {
                    Cf[(size_t)gm * ldc + gn] = v + bias[gn] + add_src[(size_t)gm * ldc + gn];
                }
            }
        }
    }
}

// ---------------- qz (absorbs hsum2) ----------------
__global__ __launch_bounds__(256) void qz_kernel(const float* __restrict__ part,
                                                 const u16* __restrict__ WqT,
                                                 const u16* __restrict__ WkT,
                                                 u16* __restrict__ z_bf) {
    int bh = blockIdx.x, b = bh >> 4, h = bh & 15;
    int tid = threadIdx.x;
    __shared__ float hm_l[1024];
    __shared__ float qs_l[64];
    __shared__ float red[256];
    {
        const float4* src = (const float4*)(part + (size_t)b * 128 * 1024) + tid;
        float4 acc = {0.f, 0.f, 0.f, 0.f};
        for (int c = 0; c < 128; c++) {
            float4 v = src[c * 256];
            acc.x += v.x; acc.y += v.y; acc.z += v.z; acc.w += v.w;
        }
        const float inv = 1.f / 2048.f;
        acc.x *= inv; acc.y *= inv; acc.z *= inv; acc.w *= inv;
        ((float4*)hm_l)[tid] = acc;
    }
    __syncthreads();
    {
        int d = tid >> 2, q = tid & 3;
        const u16* wq = WqT + (size_t)(h * 64 + d) * 1024 + q * 256;
        float a = 0.f;
        for (int i = 0; i < 256; i += 8) {
            uint4 u = *(const uint4*)(wq + i);
            const u16* p = (const u16*)&u;
            #pragma unroll
            for (int j = 0; j < 8; j++) a += bf2f(p[j]) * hm_l[q * 256 + i + j];
        }
        red[tid] = a;
    }
    __syncthreads();
    if (tid < 64)
        qs_l[tid] = red[tid * 4] + red[tid * 4 + 1] + red[tid * 4 + 2] + red[tid * 4 + 3];
    __syncthreads();
    {
        float z0 = 0.f, z1 = 0.f, z2 = 0.f, z3 = 0.f;
        for (int d = 0; d < 64; d++) {
            float qs = qs_l[d];
            const u16* wk = WkT + (size_t)(h * 64 + d) * 1024 + tid * 4;
            uint2 u = *(const uint2*)wk;
            const u16* p = (const u16*)&u;
            z0 += qs * bf2f(p[0]); z1 += qs * bf2f(p[1]);
            z2 += qs * bf2f(p[2]); z3 += qs * bf2f(p[3]);
        }
        ushort4 o;
        o.x = f2bf(z0); o.y = f2bf(z1); o.z = f2bf(z2); o.w = f2bf(z3);
        *(ushort4*)(z_bf + (size_t)bh * 1024 + tid * 4) = o;
    }
}

// ---------------- escore v3: fused enc cast + score, barrier-free (wave-private rows) ----
// grid (256,2), 256 thr. Wave w stages rows w*16..w*16+15 (its own MFMA B rows):
// fp32 load -> cvt -> ds_write (swizzled) -> ds_read B-frag. All intra-wave ordering.
__global__ __launch_bounds__(256) void escore_kernel(const float* __restrict__ enc,
                                                     const u16* __restrict__ z_bf,
                                                     u16* __restrict__ ebf,
                                                     float* __restrict__ score) {
    const int b = blockIdx.y, kv0 = blockIdx.x * 64;
    const int tid = threadIdx.x, w = tid >> 6, l = tid & 63;
    const int lr = l & 15, lg = l >> 4;
    __shared__ u16 e_lds[2][64 * 64];   // 16 KB dbuf

    const int rrel = l >> 3;     // 0..7 (rows rrel, rrel+8 within wave's 16)
    const int c8   = l & 7;      // 8-col chunk
    const float* ebase = enc + (size_t)(b * 16384 + kv0) * 1024;
    u16* obase = ebf + (size_t)(b * 16384 + kv0) * 1024;
    const u16* zb = z_bf + (size_t)b * 16 * 1024;

    float4 rv[2][2];
    auto loadT = [&](int kt) {
        #pragma unroll
        for (int j = 0; j < 2; j++) {
            int row = w * 16 + rrel + j * 8;
            rv[j][0] = *(const float4*)(ebase + (size_t)row * 1024 + kt + c8 * 8);
            rv[j][1] = *(const float4*)(ebase + (size_t)row * 1024 + kt + c8 * 8 + 4);
        }
    };
    loadT(0);

    const f32x4 fz = {0.f, 0.f, 0.f, 0.f};
    f32x4 acc = fz;

    #pragma unroll 1
    for (int t = 0; t < 16; ++t) {
        const int kt = t * 64;
        const int buf = t & 1;
        // cvt + LDS(swizzled, wave-private rows) + global ebf write
        #pragma unroll
        for (int j = 0; j < 2; j++) {
            int row = w * 16 + rrel + j * 8;
            union { u16 u[8]; uint4 v; } pk;
            pk.u[0] = f2bf(rv[j][0].x); pk.u[1] = f2bf(rv[j][0].y);
            pk.u[2] = f2bf(rv[j][0].z); pk.u[3] = f2bf(rv[j][0].w);
            pk.u[4] = f2bf(rv[j][1].x); pk.u[5] = f2bf(rv[j][1].y);
            pk.u[6] = f2bf(rv[j][1].z); pk.u[7] = f2bf(rv[j][1].w);
            *(uint4*)(e_lds[buf] + row * 64 + ((c8 ^ (row & 7)) * 8)) = pk.v;
            *(uint4*)(obase + (size_t)row * 1024 + kt + c8 * 8) = pk.v;
        }
        if (t + 1 < 16) loadT(kt + 64);   // prefetch next fp32 tile
        // MFMA on own-wave rows (compiler orders ds_write->ds_read via lgkmcnt)
        #pragma unroll
        for (int ks = 0; ks < 2; ks++) {
            bf16x8 af = *(const bf16x8*)(zb + (size_t)lr * 1024 + kt + ks * 32 + lg * 8);
            int row = w * 16 + lr;
            bf16x8 bf_ = *(const bf16x8*)(e_lds[buf] + row * 64 + (((ks * 4 + lg) ^ (row & 7))) * 8);
            acc = __builtin_amdgcn_mfma_f32_16x16x32_bf16(af, bf_, acc, 0, 0, 0);
        }
    }
    #pragma unroll
    for (int r = 0; r < 4; r++)
        score[(size_t)(b * 16 + lg * 4 + r) * 16384 + kv0 + w * 16 + lr] = acc[r];
}

// ---------------- top-2048 select: 16-bit keys, single sweep, 1024 threads ----------------
__global__ __launch_bounds__(1024) void select_kernel(const float* __restrict__ score,
                                                      int* __restrict__ sel_idx) {
    const int bh = blockIdx.x;
    const float* sc = score + (size_t)bh * 16384;
    const int tid = threadIdx.x;
    const int grp = tid >> 8;

    __shared__ int hist[4][256];
    __shared__ int total[256];
    __shared__ int bc[4];

    u16 key[16];
    #pragma unroll
    for (int j = 0; j < 16; j++) {
        unsigned int b = __float_as_uint(sc[tid + j * 1024]);
        unsigned int ui = (b & 0x80000000u) ? ~b : (b | 0x80000000u);
        key[j] = (u16)(ui >> 16);
    }

    ((int*)hist)[tid] = 0;
    __syncthreads();
    #pragma unroll
    for (int j = 0; j < 16; j++) atomicAdd(&hist[grp][key[j] >> 8], 1);
    __syncthreads();
    if (tid < 256) total[tid] = hist[0][tid] + hist[1][tid] + hist[2][tid] + hist[3][tid];
    __syncthreads();
    if (tid == 0) {
        int want = 2048, acc = 0;
        for (int dd = 255; dd >= 0; dd--) {
            acc += total[dd];
            if (acc >= want) { bc[0] = dd; bc[1] = want - (acc - total[dd]); break; }
        }
    }
    __syncthreads();
    const int hi = bc[0];
    const int want1 = bc[1];

    ((int*)hist)[tid] = 0;
    __syncthreads();
    #pragma unroll
    for (int j = 0; j < 16; j++)
        if ((key[j] >> 8) == hi) atomicAdd(&hist[grp][key[j] & 0xff], 1);
    __syncthreads();
    if (tid < 256) total[tid] = hist[0][tid] + hist[1][tid] + hist[2][tid] + hist[3][tid];
    __syncthreads();
    if (tid == 0) {
        int want = want1, acc = 0;
        for (int dd = 255; dd >= 0; dd--) {
            acc += total[dd];
            if (acc >= want) { bc[0] = (hi << 8) | dd; bc[1] = want - (acc - total[dd]); break; }
        }
        bc[2] = 0; bc[3] = 0;
    }
    __syncthreads();
    const u16 thr = (u16)bc[0];
    const int n_eq = bc[1];
    const int base_eq = 2048 - n_eq;

    int* out = sel_idx + (size_t)bh * 2048;
    #pragma unroll
    for (int j = 0; j < 16; j++) {
        int i = tid + j * 1024;
        if (key[j] > thr) {
            int p = atomicAdd(&bc[2], 1);
            out[p] = i;
        } else if (key[j] == thr) {
            int p = atomicAdd(&bc[3], 1);
            if (p < n_eq) out[base_eq + p] = i;
        }
    }
}

// ---------------- selected projection (single-buffer): K_sel + V_selT(kappa) ----------------
__global__ __launch_bounds__(256) void selproj_kernel(const u16* __restrict__ ebf,
                                                      const u16* __restrict__ WkvT,
                                                      const int* __restrict__ sel_idx,
                                                      u16* __restrict__ k_sel,
                                                      u16* __restrict__ v_selT) {
    const int bh = blockIdx.y, b = bh >> 4, h = bh & 15;
    const int t0 = blockIdx.x * 128;
    const int tid = threadIdx.x, w = tid >> 6, l = tid & 63;
    const int lr = l & 15, lg = l >> 4;
    const int lane_row = l >> 3, src_ch = (l & 7) ^ lane_row;

    __shared__ u16 e_lds[128 * 64];
    __shared__ u16 w_lds[128 * 64];

    int encrow[4], wrow[4];
    #pragma unroll
    for (int j = 0; j < 4; j++) {
        int t = t0 + w * 32 + j * 8 + lane_row;
        encrow[j] = b * 16384 + sel_idx[(size_t)bh * 2048 + t];
        int r = w * 32 + j * 8 + lane_row;
        wrow[j] = (r < 64) ? (h * 64 + r) : (1024 + h * 64 + (r & 63));
    }

    const f32x4 fz = {0.f, 0.f, 0.f, 0.f};
    f32x4 acc_k[2][4], acc_v[8];
    #pragma unroll
    for (int i = 0; i < 2; i++)
        #pragma unroll
        for (int j = 0; j < 4; j++) acc_k[i][j] = fz;
    #pragma unroll
    for (int i = 0; i < 8; i++) acc_v[i] = fz;

    for (int kt = 0; kt < 1024; kt += 64) {
        __syncthreads();
        #pragma unroll
        for (int j = 0; j < 4; j++) {
            glds16(ebf + (size_t)encrow[j] * 1024 + kt + src_ch * 8, e_lds + (w * 32 + j * 8) * 64);
            glds16(WkvT + (size_t)wrow[j] * 1024 + kt + src_ch * 8, w_lds + (w * 32 + j * 8) * 64);
        }
        __syncthreads();
        #pragma unroll
        for (int ks = 0; ks < 2; ks++) {
            bf16x8 ae[2];
            #pragma unroll
            for (int mi = 0; mi < 2; mi++) {
                int row = w * 32 + mi * 16 + lr;
                ae[mi] = *(const bf16x8*)(e_lds + row * 64 + (((ks * 4 + lg) ^ (row & 7))) * 8);
            }
            bf16x8 aw;
            {
                int row = 64 + w * 16 + lr;
                aw = *(const bf16x8*)(w_lds + row * 64 + (((ks * 4 + lg) ^ (row & 7))) * 8);
            }
            #pragma unroll
            for (int ni = 0; ni < 4; ni++) {
                int row = ni * 16 + lr;
                bf16x8 bw = *(const bf16x8*)(w_lds + row * 64 + (((ks * 4 + lg) ^ (row & 7))) * 8);
                acc_k[0][ni] = __builtin_amdgcn_mfma_f32_16x16x32_bf16(ae[0], bw, acc_k[0][ni], 0, 0, 0);
                acc_k[1][ni] = __builtin_amdgcn_mfma_f32_16x16x32_bf16(ae[1], bw, acc_k[1][ni], 0, 0, 0);
            }
            #pragma unroll
            for (int ni = 0; ni < 8; ni++) {
                int row = ni * 16 + lr;
                bf16x8 be = *(const bf16x8*)(e_lds + row * 64 + (((ks * 4 + lg) ^ (row & 7))) * 8);
                acc_v[ni] = __builtin_amdgcn_mfma_f32_16x16x32_bf16(aw, be, acc_v[ni], 0, 0, 0);
            }
        }
    }

    u16* kb = k_sel + (size_t)bh * 2048 * 64;
    #pragma unroll
    for (int mi = 0; mi < 2; mi++)
        #pragma unroll
        for (int ni = 0; ni < 4; ni++)
            #pragma unroll
            for (int r = 0; r < 4; r++) {
                int t = t0 + w * 32 + mi * 16 + lg * 4 + r;
                int d = ni * 16 + lr;
                kb[(size_t)t * 64 + (((d >> 3) ^ (t & 7)) * 8) + (d & 7)] = f2bf(acc_k[mi][ni][r]);
            }
    u16* vb = v_selT + (size_t)bh * 64 * 2048;
    #pragma unroll
    for (int ni = 0; ni < 8; ni++)
        #pragma unroll
        for (int r = 0; r < 4; r++) {
            int d = w * 16 + lg * 4 + r;
            int t = t0 + ni * 16 + lr;
            int tl = t & 63;
            int kap = (tl & 15) * 4 + (tl >> 4);
            vb[(size_t)d * 2048 + (t & ~63) + (((kap >> 3) ^ (d & 7)) * 8) + (kap & 7)] =
                f2bf(acc_v[ni][r]);
        }
}

// ---------------- flash attention: 8 waves, QBLK=128, kappa-packed P store ----------------
__global__ __launch_bounds__(512) void attn_kernel(
    const u16* __restrict__ q_bf, const u16* __restrict__ k_sel,
    const u16* __restrict__ v_selT, u16* __restrict__ attn_out) {
    const int bh = blockIdx.y, b = bh >> 4, h = bh & 15;
    const int q0 = blockIdx.x * 128;
    const int tid = threadIdx.x, w = tid >> 6, l = tid & 63;
    const int lr = l & 15, lg = l >> 4;
    const int lk = lr & 7;
    const float SC = 0.18033688011f;   // 0.125 * log2(e)
    const float THR = 11.0f;

    __shared__ u16 k_lds[2][64 * 64];
    __shared__ u16 vt_lds[64 * 64];
    __shared__ u16 p_lds[8][16][68];

    const u16* qb = q_bf + ((size_t)b * 2048 + q0 + w * 16 + lr) * 1024 + h * 64;
    bf16x8 qf0 = *(const bf16x8*)(qb + lg * 8);
    bf16x8 qf1 = *(const bf16x8*)(qb + 32 + lg * 8);

    const f32x4 fz = {0.f, 0.f, 0.f, 0.f};
    f32x4 o[4];
    #pragma unroll
    for (int f = 0; f < 4; f++) o[f] = fz;
    float mm = -1e30f;
    float l_part[4] = {0.f, 0.f, 0.f, 0.f};

    const u16* kb  = k_sel + (size_t)bh * 2048 * 64;
    const u16* vtb = v_selT + (size_t)bh * 64 * 2048;

    auto stageK = [&](int it, int buf) {
        const u16* ksrc = kb + (size_t)(it * 64 + w * 8) * 64 + (size_t)l * 8;
        glds16(ksrc, k_lds[buf] + (w * 8) * 64);
    };
    auto stageV = [&](int it) {
        const u16* vsrc = vtb + (size_t)(w * 8 + (l >> 3)) * 2048 + it * 64 + (l & 7) * 8;
        glds16(vsrc, vt_lds + (w * 8) * 64);
    };

    stageK(0, 0);
    __syncthreads();

    #pragma unroll 1
    for (int it = 0; it < 32; ++it) {
        const int cur = it & 1;
        stageV(it);
        if (it + 1 < 32) stageK(it + 1, cur ^ 1);

        f32x4 s[4];
        #pragma unroll
        for (int c = 0; c < 4; c++) s[c] = fz;
        __builtin_amdgcn_s_setprio(1);
        #pragma unroll
        for (int c = 0; c < 4; c++) {
            const u16* krow = k_lds[cur] + (c * 16 + lr) * 64;
            bf16x8 kf0 = *(const bf16x8*)(krow + (lg ^ lk) * 8);
            s[c] = __builtin_amdgcn_mfma_f32_16x16x32_bf16(qf0, kf0, s[c], 0, 0, 0);
            bf16x8 kf1 = *(const bf16x8*)(krow + (((4 + lg) ^ lk)) * 8);
            s[c] = __builtin_amdgcn_mfma_f32_16x16x32_bf16(qf1, kf1, s[c], 0, 0, 0);
        }
        __builtin_amdgcn_s_setprio(0);

        float mx = s[0][0];
        #pragma unroll
        for (int c = 0; c < 4; c++)
            #pragma unroll
            for (int r = 0; r < 4; r++) mx = fmaxf(mx, s[c][r]);
        mx = fmaxf(mx, __shfl_xor(mx, 1));
        mx = fmaxf(mx, __shfl_xor(mx, 2));
        mx = fmaxf(mx, __shfl_xor(mx, 4));
        mx = fmaxf(mx, __shfl_xor(mx, 8));
        mx = fmaxf(mx, __shfl_xor(mx, 16));
        mx = fmaxf(mx, __shfl_xor(mx, 32));
        mx *= SC;
        if (mx > mm + THR) {
            float al = __builtin_amdgcn_exp2f(mm - mx);
            mm = mx;
            #pragma unroll
            for (int r = 0; r < 4; r++) l_part[r] *= al;
            #pragma unroll
            for (int f = 0; f < 4; f++)
                #pragma unroll
                for (int r = 0; r < 4; r++) o[f][r] *= al;
        }
        #pragma unroll
        for (int r = 0; r < 4; r++) {
            ushort4 pk;
            u16 pb[4];
            #pragma unroll
            for (int c = 0; c < 4; c++) {
                float p = __builtin_amdgcn_exp2f(__builtin_fmaf(s[c][r], SC, -mm));
                l_part[r] += p;
                __bf16 hv = (__bf16)p;
                pb[c] = *(u16*)&hv;
            }
            pk.x = pb[0]; pk.y = pb[1]; pk.z = pb[2]; pk.w = pb[3];
            *(ushort4*)(&p_lds[w][lg * 4 + r][lr * 4]) = pk;
        }

        if (it + 1 < 32) {
            asm volatile("s_waitcnt vmcnt(1)" ::: "memory");
        } else {
            asm volatile("s_waitcnt vmcnt(0)" ::: "memory");
        }
        __builtin_amdgcn_sched_barrier(0);
        __builtin_amdgcn_s_barrier();

        __builtin_amdgcn_s_setprio(1);
        #pragma unroll
        for (int kk = 0; kk < 2; kk++) {
            bf16x8 ap = *(const bf16x8*)(&p_lds[w][lr][kk * 32 + lg * 8]);
            #pragma unroll
            for (int f = 0; f < 4; f++) {
                const u16* vrow = vt_lds + (f * 16 + lr) * 64;
                bf16x8 bv = *(const bf16x8*)(vrow + (((kk * 4 + lg) ^ lk)) * 8);
                o[f] = __builtin_amdgcn_mfma_f32_16x16x32_bf16(ap, bv, o[f], 0, 0, 0);
            }
        }
        __builtin_amdgcn_s_setprio(0);

        __syncthreads();
    }

    float invl[4];
    #pragma unroll
    for (int r = 0; r < 4; r++) {
        float lr_ = l_part[r];
        lr_ += __shfl_xor(lr_, 1);
        lr_ += __shfl_xor(lr_, 2);
        lr_ += __shfl_xor(lr_, 4);
        lr_ += __shfl_xor(lr_, 8);
        invl[r] = 1.f / lr_;
    }
    u16* ob = attn_out + ((size_t)b * 2048 + q0 + w * 16 + lg * 4) * 1024 + h * 64 + lr;
    #pragma unroll
    for (int f = 0; f < 4; f++) {
        #pragma unroll
        for (int r = 0; r < 4; r++) {
            __bf16 hv = (__bf16)(o[f][r] * invl[r]);
            ob[(size_t)r * 1024 + f * 16] = *(u16*)&hv;
        }
    }
}

// ---------------- launcher ----------------
extern "C" void kernel_launch(void* const* d_in, const int* in_sizes, int n_in,
                              void* d_out, int out_size, void* d_ws, size_t ws_size,
                              hipStream_t stream) {
    const float* hidden = (const float*)d_in[0];
    const float* enc    = (const float*)d_in[1];
    const float* Wq = (const float*)d_in[2];
    const float* Wk = (const float*)d_in[3];
    const float* Wv = (const float*)d_in[4];
    const float* Wo = (const float*)d_in[5];
    const float* bo = (const float*)d_in[6];
    const float* Wg = (const float*)d_in[7];
    const float* bg = (const float*)d_in[8];
    float* out = (float*)d_out;

    char* ws = (char*)d_ws;
    size_t off = 0;
    auto alloc = [&](size_t bytes) -> char* {
        char* p = ws + off;
        off += (bytes + 255) & ~(size_t)255;
        return p;
    };
    u16* hbf   = (u16*)alloc(4096ull * 1024 * 2);
    u16* ebf   = (u16*)alloc(32768ull * 1024 * 2);
    u16* WqT   = (u16*)alloc(1024ull * 1024 * 2);
    u16* WkvT  = (u16*)alloc(2048ull * 1024 * 2);
    u16* WgT   = (u16*)alloc(1024ull * 1024 * 2);
    u16* WoT   = (u16*)alloc(1024ull * 1024 * 2);
    u16* q_bf  = (u16*)alloc(4096ull * 1024 * 2);
    float* part = (float*)alloc(2ull * 128 * 1024 * 4);
    u16* z_bf  = (u16*)alloc(32ull * 1024 * 2);
    float* scor = (float*)alloc(32ull * 16384 * 4);
    int* sel    = (int*)alloc(32ull * 2048 * 4);
    u16* ksel   = (u16*)alloc(32ull * 2048 * 64 * 2);
    u16* vT     = (u16*)alloc(32ull * 64 * 2048 * 2);
    u16* attn   = (u16*)alloc(4096ull * 1024 * 2);
    u16* gate   = (u16*)alloc(4096ull * 1024 * 2);
    (void)ws_size; (void)in_sizes; (void)n_in; (void)out_size;

    prep_kernel<<<dim3(2, 128), 256, 0, stream>>>(hidden, hbf, part);
    transpose_cast_kernel<<<dim3(32, 32, 5), dim3(32, 8), 0, stream>>>(
        Wq, Wk, Wv, Wg, Wo, WqT, WkvT, WgT, WoT);

    qz_kernel<<<32, 256, 0, stream>>>(part, WqT, WkvT, z_bf);
    escore_kernel<<<dim3(256, 2), 256, 0, stream>>>(enc, z_bf, ebf, scor);
    select_kernel<<<32, 1024, 0, stream>>>(scor, sel);
    selproj_kernel<<<dim3(16, 32), 256, 0, stream>>>(ebf, WkvT, sel, ksel, vT);

    gemm_bf16<0><<<dim3(16, 32), 256, 0, stream>>>(hbf, WqT, 1024, q_bf, nullptr, nullptr, nullptr, nullptr);
    attn_kernel<<<dim3(16, 32), 512, 0, stream>>>(q_bf, ksel, vT, attn);

    gemm_bf16<2><<<dim3(16, 32), 256, 0, stream>>>(attn, WgT, 1024, gate, bg, attn, nullptr, nullptr);
    gemm_bf16<3><<<dim3(16, 32), 256, 0, stream>>>(gate, WoT, 1024, nullptr, bo, nullptr, hidden, out);
}